// Round 1
// baseline (647.281 us; speedup 1.0000x reference)
//
#include <hip/hip_runtime.h>

typedef unsigned short u16;
typedef __bf16 bf16x8 __attribute__((ext_vector_type(8)));
typedef short  s16x8  __attribute__((ext_vector_type(8)));
typedef float  f32x4  __attribute__((ext_vector_type(4)));

#define LDSPAD 72   // 64 + 8 bf16 pad: keeps 16B alignment, breaks 128B-stride bank conflict

static __device__ __forceinline__ u16 f2bf(float f){
  union { float f; unsigned int u; } v; v.f = f;
  unsigned int r = v.u + 0x7fffu + ((v.u >> 16) & 1u);
  return (u16)(r >> 16);
}
static __device__ __forceinline__ float bf2f(u16 u){
  union { unsigned int u; float f; } v; v.u = ((unsigned int)u) << 16; return v.f;
}

// ---------------- weight transpose + fp32 -> bf16 (out = in^T) ----------------
__global__ __launch_bounds__(256) void wtrans_kernel(const float* __restrict__ in,
                                                     u16* __restrict__ out, int K, int N){
  // in: K x N (row-major), out: N x K (row-major)
  __shared__ float tile[32][33];
  int n0 = blockIdx.x * 32, k0 = blockIdx.y * 32;
  int tx = threadIdx.x, ty = threadIdx.y;     // block (32, 8)
  #pragma unroll
  for (int i = 0; i < 4; ++i)
    tile[ty + i*8][tx] = in[(size_t)(k0 + ty + i*8) * N + n0 + tx];
  __syncthreads();
  #pragma unroll
  for (int i = 0; i < 4; ++i)
    out[(size_t)(n0 + ty + i*8) * K + k0 + tx] = f2bf(tile[tx][ty + i*8]);
}

// ---------------- RMSNorm: fp32 in -> bf16 out ----------------
__global__ __launch_bounds__(256) void rmsnorm_kernel(const float* __restrict__ x,
                                                      const float* __restrict__ gamma,
                                                      u16* __restrict__ out){
  int row = blockIdx.x;                        // 8192 rows, D=1024
  const float* xr = x + (size_t)row * 1024;
  int tid = threadIdx.x;
  float4 xv = *(const float4*)(xr + tid * 4);
  float ss = xv.x*xv.x + xv.y*xv.y + xv.z*xv.z + xv.w*xv.w;
  #pragma unroll
  for (int off = 1; off < 64; off <<= 1) ss += __shfl_xor(ss, off);
  __shared__ float wsum[4];
  if ((tid & 63) == 0) wsum[tid >> 6] = ss;
  __syncthreads();
  float tot = wsum[0] + wsum[1] + wsum[2] + wsum[3];
  float r = rsqrtf(tot * (1.0f/1024.0f) + 1e-6f);
  const float4 gv = *(const float4*)(gamma + tid * 4);
  u16* o = out + (size_t)row * 1024 + tid * 4;
  o[0] = f2bf(xv.x * r * gv.x);
  o[1] = f2bf(xv.y * r * gv.y);
  o[2] = f2bf(xv.z * r * gv.z);
  o[3] = f2bf(xv.w * r * gv.w);
}

// ---------------- generic bf16 GEMM: C = A(MxK) * Bt(NxK)^T ----------------
// EPI: 0 none->bf16, 1 +bias->bf16, 2 +bias,relu->bf16, 3 +bias,+resid->fp32
template<int EPI>
__global__ __launch_bounds__(256) void gemm_bt_kernel(
    const u16* __restrict__ A, int lda,
    const u16* __restrict__ Bt,
    const float* __restrict__ bias,
    const float* __restrict__ resid,
    u16* __restrict__ outb, float* __restrict__ outf,
    int N, int K)
{
  __shared__ __align__(16) u16 As[64][LDSPAD];
  __shared__ __align__(16) u16 Bs[64][LDSPAD];
  int tid = threadIdx.x;
  int wid = tid >> 6, lane = tid & 63;
  int fr = lane & 15, fq = lane >> 4;
  int m0 = blockIdx.x * 64, n0 = blockIdx.y * 64;
  int srow = tid >> 2, scol = (tid & 3) * 8;
  f32x4 acc[4];
  #pragma unroll
  for (int i = 0; i < 4; ++i) acc[i] = (f32x4){0.f, 0.f, 0.f, 0.f};

  for (int k0 = 0; k0 < K; k0 += 64){
    __syncthreads();
    const u16* ap = A + (size_t)(m0 + srow) * lda + k0 + scol;
    *(bf16x8*)&As[srow][scol]      = *(const bf16x8*)(ap);
    *(bf16x8*)&As[srow][scol + 32] = *(const bf16x8*)(ap + 32);
    const u16* bp = Bt + (size_t)(n0 + srow) * K + k0 + scol;
    *(bf16x8*)&Bs[srow][scol]      = *(const bf16x8*)(bp);
    *(bf16x8*)&Bs[srow][scol + 32] = *(const bf16x8*)(bp + 32);
    __syncthreads();
    #pragma unroll
    for (int ks = 0; ks < 2; ++ks){
      bf16x8 af = *(const bf16x8*)&As[wid*16 + fr][ks*32 + fq*8];
      #pragma unroll
      for (int nt = 0; nt < 4; ++nt){
        bf16x8 bv = *(const bf16x8*)&Bs[nt*16 + fr][ks*32 + fq*8];
        acc[nt] = __builtin_amdgcn_mfma_f32_16x16x32_bf16(af, bv, acc[nt], 0, 0, 0);
      }
    }
  }
  // D layout: row = fq*4 + j, col = fr (verified m89 mapping)
  #pragma unroll
  for (int nt = 0; nt < 4; ++nt){
    int col = n0 + nt*16 + fr;
    float bv = (EPI >= 1) ? bias[col] : 0.0f;
    #pragma unroll
    for (int j = 0; j < 4; ++j){
      int row = m0 + wid*16 + fq*4 + j;
      float vv = acc[nt][j] + bv;
      if (EPI == 2) vv = fmaxf(vv, 0.0f);
      size_t idx = (size_t)row * N + col;
      if (EPI == 3) outf[idx] = vv + resid[idx];
      else          outb[idx] = f2bf(vv);
    }
  }
}

// ---------------- fused flash attention ----------------
// q,k,v: (B*S, H*64) bf16 row-major. ctx out: (B*S, H*64) bf16.
__global__ __launch_bounds__(256) void attn_kernel(
    const u16* __restrict__ q, const u16* __restrict__ k,
    const u16* __restrict__ v, const int* __restrict__ mask,
    u16* __restrict__ ctx)
{
  __shared__ __align__(16) u16 Ks[64][LDSPAD];
  __shared__ __align__(16) u16 Vs[64][LDSPAD];
  __shared__ __align__(16) u16 Ps[64][LDSPAD];
  int tid = threadIdx.x;
  int wid = tid >> 6, lane = tid & 63;
  int fr = lane & 15, fq = lane >> 4;
  int q0 = blockIdx.x * 64;
  int bh = blockIdx.y;
  int b = bh >> 4, h = bh & 15;
  const size_t base = ((size_t)b * 1024) * 1024 + (size_t)h * 64;  // + s*1024 + d
  int srow = tid >> 2, scol = (tid & 3) * 8;

  bf16x8 qf[2];
  {
    const u16* qp = q + base + (size_t)(q0 + wid*16 + fr) * 1024 + fq * 8;
    qf[0] = *(const bf16x8*)(qp);
    qf[1] = *(const bf16x8*)(qp + 32);
  }
  f32x4 acc_o[4];
  #pragma unroll
  for (int i = 0; i < 4; ++i) acc_o[i] = (f32x4){0.f, 0.f, 0.f, 0.f};
  float mrow[4], lrow[4];
  #pragma unroll
  for (int j = 0; j < 4; ++j){ mrow[j] = -1e30f; lrow[j] = 0.f; }
  const float scale = 0.125f;  // 1/sqrt(64)

  for (int t = 0; t < 16; ++t){
    int kv0 = t * 64;
    __syncthreads();
    const u16* kp = k + base + (size_t)(kv0 + srow) * 1024 + scol;
    *(bf16x8*)&Ks[srow][scol]      = *(const bf16x8*)(kp);
    *(bf16x8*)&Ks[srow][scol + 32] = *(const bf16x8*)(kp + 32);
    const u16* vp = v + base + (size_t)(kv0 + srow) * 1024 + scol;
    *(bf16x8*)&Vs[srow][scol]      = *(const bf16x8*)(vp);
    *(bf16x8*)&Vs[srow][scol + 32] = *(const bf16x8*)(vp + 32);
    __syncthreads();

    f32x4 sc[4];
    #pragma unroll
    for (int nt = 0; nt < 4; ++nt) sc[nt] = (f32x4){0.f, 0.f, 0.f, 0.f};
    #pragma unroll
    for (int ks = 0; ks < 2; ++ks){
      #pragma unroll
      for (int nt = 0; nt < 4; ++nt){
        bf16x8 bv = *(const bf16x8*)&Ks[nt*16 + fr][ks*32 + fq*8];
        sc[nt] = __builtin_amdgcn_mfma_f32_16x16x32_bf16(qf[ks], bv, sc[nt], 0, 0, 0);
      }
    }
    float mvals[4];
    #pragma unroll
    for (int nt = 0; nt < 4; ++nt)
      mvals[nt] = (mask[b * 1024 + kv0 + nt*16 + fr] == 0) ? -1e9f : 0.f;

    float pj[4][4];   // [nt][j]
    #pragma unroll
    for (int j = 0; j < 4; ++j){
      float rmax = -1e30f;
      #pragma unroll
      for (int nt = 0; nt < 4; ++nt){
        float s = sc[nt][j] * scale + mvals[nt];
        pj[nt][j] = s;
        rmax = fmaxf(rmax, s);
      }
      rmax = fmaxf(rmax, __shfl_xor(rmax, 1));
      rmax = fmaxf(rmax, __shfl_xor(rmax, 2));
      rmax = fmaxf(rmax, __shfl_xor(rmax, 4));
      rmax = fmaxf(rmax, __shfl_xor(rmax, 8));
      float mnew = fmaxf(mrow[j], rmax);
      float corr = __expf(mrow[j] - mnew);
      float rsum = 0.f;
      #pragma unroll
      for (int nt = 0; nt < 4; ++nt){
        float p = __expf(pj[nt][j] - mnew);
        pj[nt][j] = p;
        rsum += p;
      }
      rsum += __shfl_xor(rsum, 1);
      rsum += __shfl_xor(rsum, 2);
      rsum += __shfl_xor(rsum, 4);
      rsum += __shfl_xor(rsum, 8);
      lrow[j] = lrow[j] * corr + rsum;
      mrow[j] = mnew;
      #pragma unroll
      for (int nt = 0; nt < 4; ++nt) acc_o[nt][j] *= corr;
    }
    // write P tile (bf16) — wave-local rows, but barrier for safety
    #pragma unroll
    for (int j = 0; j < 4; ++j)
      #pragma unroll
      for (int nt = 0; nt < 4; ++nt)
        Ps[wid*16 + fq*4 + j][nt*16 + fr] = f2bf(pj[nt][j]);
    __syncthreads();
    // PV
    #pragma unroll
    for (int ks = 0; ks < 2; ++ks){
      bf16x8 af = *(const bf16x8*)&Ps[wid*16 + fr][ks*32 + fq*8];
      #pragma unroll
      for (int nt = 0; nt < 4; ++nt){
        s16x8 tmp;
        #pragma unroll
        for (int j = 0; j < 8; ++j)
          tmp[j] = (short)Vs[ks*32 + fq*8 + j][nt*16 + fr];
        bf16x8 bv = __builtin_bit_cast(bf16x8, tmp);
        acc_o[nt] = __builtin_amdgcn_mfma_f32_16x16x32_bf16(af, bv, acc_o[nt], 0, 0, 0);
      }
    }
  }
  #pragma unroll
  for (int nt = 0; nt < 4; ++nt)
    #pragma unroll
    for (int j = 0; j < 4; ++j){
      float o = acc_o[nt][j] / lrow[j];
      ctx[base + (size_t)(q0 + wid*16 + fq*4 + j) * 1024 + nt*16 + fr] = f2bf(o);
    }
}

// ---------------- depthwise dilated conv (K=4, dil=2, pad 3) + gate, in-place over sec ----------------
__global__ __launch_bounds__(256) void convgate_kernel(
    const u16* __restrict__ f, const float* __restrict__ cw,
    const float* __restrict__ cb, u16* __restrict__ sec_inout)
{
  size_t gid = (size_t)blockIdx.x * blockDim.x + threadIdx.x;  // 2M threads, 8 ch each
  int c0 = (int)(gid & 255) * 8;
  int t  = (int)((gid >> 8) & 1023);
  int b  = (int)(gid >> 18);
  const u16* fb = f + ((size_t)b * 1024) * 2048;
  float acc[8];
  #pragma unroll
  for (int e = 0; e < 8; ++e) acc[e] = cb[c0 + e];
  #pragma unroll
  for (int j = 0; j < 4; ++j){
    int tt = t - 3 + 2 * j;
    if (tt >= 0 && tt < 1024){
      s16x8 fv = *(const s16x8*)(fb + (size_t)tt * 2048 + c0);
      #pragma unroll
      for (int e = 0; e < 8; ++e) acc[e] += bf2f((u16)fv[e]) * cw[(c0 + e) * 4 + j];
    }
  }
  u16* sp = sec_inout + (((size_t)b * 1024 + t) * 2048 + c0);
  s16x8 sv = *(const s16x8*)sp;
  s16x8 ov;
  #pragma unroll
  for (int e = 0; e < 8; ++e) ov[e] = (short)f2bf(acc[e] * bf2f((u16)sv[e]));
  *(s16x8*)sp = ov;
}

// ---------------- host launch ----------------
extern "C" void kernel_launch(void* const* d_in, const int* in_sizes, int n_in,
                              void* d_out, int out_size, void* d_ws, size_t ws_size,
                              hipStream_t stream)
{
  const float* x     = (const float*)d_in[0];
  const int*   mask  = (const int*)  d_in[1];
  const float* gamma = (const float*)d_in[2];
  const float* wq    = (const float*)d_in[3];
  const float* wk    = (const float*)d_in[4];
  const float* wv    = (const float*)d_in[5];
  const float* wo    = (const float*)d_in[6];
  const float* w1    = (const float*)d_in[7];
  const float* b1    = (const float*)d_in[8];
  const float* cw    = (const float*)d_in[9];
  const float* cb    = (const float*)d_in[10];
  const float* w2    = (const float*)d_in[11];
  const float* b2    = (const float*)d_in[12];
  const float* wp    = (const float*)d_in[13];
  const float* bp    = (const float*)d_in[14];
  float* out = (float*)d_out;

  char* p = (char*)d_ws;
  auto alloc = [&](size_t bytes){ char* r = p; p += (bytes + 255) & ~(size_t)255; return r; };
  u16* wqT = (u16*)alloc((size_t)1024*1024*2);
  u16* wkT = (u16*)alloc((size_t)1024*1024*2);
  u16* wvT = (u16*)alloc((size_t)1024*1024*2);
  u16* woT = (u16*)alloc((size_t)1024*1024*2);
  u16* w1T = (u16*)alloc((size_t)2048*512*2);
  u16* w2T = (u16*)alloc((size_t)2048*512*2);
  u16* wpT = (u16*)alloc((size_t)1024*2048*2);
  u16* nrm = (u16*)alloc((size_t)8192*1024*2);   // later: ctx
  u16* qb  = (u16*)alloc((size_t)8192*1024*2);   // later: attn out proj
  u16* kb  = (u16*)alloc((size_t)8192*1024*2);   // later: f (spans kb+vb)
  u16* vb  = (u16*)alloc((size_t)8192*1024*2);
  u16* sec = (u16*)alloc((size_t)8192*2048*2);   // later: gated (in-place)
  (void)vb; (void)ws_size; (void)in_sizes; (void)n_in; (void)out_size;

  dim3 tb32(32, 8);
  wtrans_kernel<<<dim3(32, 32), tb32, 0, stream>>>(wq, wqT, 1024, 1024);
  wtrans_kernel<<<dim3(32, 32), tb32, 0, stream>>>(wk, wkT, 1024, 1024);
  wtrans_kernel<<<dim3(32, 32), tb32, 0, stream>>>(wv, wvT, 1024, 1024);
  wtrans_kernel<<<dim3(32, 32), tb32, 0, stream>>>(wo, woT, 1024, 1024);
  wtrans_kernel<<<dim3(64, 16), tb32, 0, stream>>>(w1, w1T, 512, 2048);
  wtrans_kernel<<<dim3(64, 16), tb32, 0, stream>>>(w2, w2T, 512, 2048);
  wtrans_kernel<<<dim3(32, 64), tb32, 0, stream>>>(wp, wpT, 2048, 1024);

  rmsnorm_kernel<<<8192, 256, 0, stream>>>(x, gamma, nrm);

  gemm_bt_kernel<0><<<dim3(128, 16), 256, 0, stream>>>(nrm, 1024, wqT, nullptr, nullptr, qb, nullptr, 1024, 1024);
  gemm_bt_kernel<0><<<dim3(128, 16), 256, 0, stream>>>(nrm, 1024, wkT, nullptr, nullptr, kb, nullptr, 1024, 1024);
  gemm_bt_kernel<0><<<dim3(128, 16), 256, 0, stream>>>(nrm, 1024, wvT, nullptr, nullptr, vb, nullptr, 1024, 1024);

  attn_kernel<<<dim3(16, 128), 256, 0, stream>>>(qb, kb, vb, mask, nrm);

  gemm_bt_kernel<0><<<dim3(128, 16), 256, 0, stream>>>(nrm, 1024, woT, nullptr, nullptr, qb, nullptr, 1024, 1024);

  gemm_bt_kernel<1><<<dim3(128, 32), 256, 0, stream>>>(qb,       1024, w1T, b1, nullptr, kb,  nullptr, 2048, 512);
  gemm_bt_kernel<2><<<dim3(128, 32), 256, 0, stream>>>(qb + 512, 1024, w2T, b2, nullptr, sec, nullptr, 2048, 512);

  convgate_kernel<<<8192, 256, 0, stream>>>(kb, cw, cb, sec);

  gemm_bt_kernel<3><<<dim3(128, 16), 256, 0, stream>>>(sec, 2048, wpT, bp, x, nullptr, out, 1024, 2048);
}

// Round 2
// 516.068 us; speedup vs baseline: 1.2543x; 1.2543x over previous
//
#include <hip/hip_runtime.h>

typedef unsigned short u16;
typedef __bf16 bf16x8 __attribute__((ext_vector_type(8)));
typedef short  s16x8  __attribute__((ext_vector_type(8)));
typedef float  f32x4  __attribute__((ext_vector_type(4)));

#define LDSPAD 72   // 64 + 8 bf16 pad for attn tiles

// async global->LDS, 16B per lane, LDS dest = wave-uniform base + lane*16
#define GLOAD16(gp, lp) __builtin_amdgcn_global_load_lds( \
  (__attribute__((address_space(1))) unsigned int*)(unsigned long long)(const void*)(gp), \
  (__attribute__((address_space(3))) unsigned int*)(lp), 16, 0, 0)

static __device__ __forceinline__ u16 f2bf(float f){
  union { float f; unsigned int u; } v; v.f = f;
  unsigned int r = v.u + 0x7fffu + ((v.u >> 16) & 1u);
  return (u16)(r >> 16);
}
static __device__ __forceinline__ float bf2f(u16 u){
  union { unsigned int u; float f; } v; v.u = ((unsigned int)u) << 16; return v.f;
}

// ---------------- weight transpose + fp32 -> bf16 (out = in^T) ----------------
__global__ __launch_bounds__(256) void wtrans_kernel(const float* __restrict__ in,
                                                     u16* __restrict__ out, int K, int N){
  __shared__ float tile[32][33];
  int n0 = blockIdx.x * 32, k0 = blockIdx.y * 32;
  int tx = threadIdx.x, ty = threadIdx.y;     // block (32, 8)
  #pragma unroll
  for (int i = 0; i < 4; ++i)
    tile[ty + i*8][tx] = in[(size_t)(k0 + ty + i*8) * N + n0 + tx];
  __syncthreads();
  #pragma unroll
  for (int i = 0; i < 4; ++i)
    out[(size_t)(n0 + ty + i*8) * K + k0 + tx] = f2bf(tile[tx][ty + i*8]);
}

// ---------------- bf16 transpose (for V^T): in R x C -> out C x R ----------------
__global__ __launch_bounds__(256) void btrans_kernel(const u16* __restrict__ in, int istride, int ioff,
                                                     u16* __restrict__ out, int R, int C){
  __shared__ u16 tile[32][33];
  int c0 = blockIdx.x * 32, r0 = blockIdx.y * 32;
  int tx = threadIdx.x, ty = threadIdx.y;     // block (32, 8)
  #pragma unroll
  for (int i = 0; i < 4; ++i)
    tile[ty + i*8][tx] = in[(size_t)(r0 + ty + i*8) * istride + ioff + c0 + tx];
  __syncthreads();
  #pragma unroll
  for (int i = 0; i < 4; ++i)
    out[(size_t)(c0 + ty + i*8) * R + r0 + tx] = tile[tx][ty + i*8];
}

// ---------------- RMSNorm: fp32 in -> bf16 out ----------------
__global__ __launch_bounds__(256) void rmsnorm_kernel(const float* __restrict__ x,
                                                      const float* __restrict__ gamma,
                                                      u16* __restrict__ out){
  int row = blockIdx.x;                        // 8192 rows, D=1024
  const float* xr = x + (size_t)row * 1024;
  int tid = threadIdx.x;
  float4 xv = *(const float4*)(xr + tid * 4);
  float ss = xv.x*xv.x + xv.y*xv.y + xv.z*xv.z + xv.w*xv.w;
  #pragma unroll
  for (int off = 1; off < 64; off <<= 1) ss += __shfl_xor(ss, off);
  __shared__ float wsum[4];
  if ((tid & 63) == 0) wsum[tid >> 6] = ss;
  __syncthreads();
  float tot = wsum[0] + wsum[1] + wsum[2] + wsum[3];
  float r = rsqrtf(tot * (1.0f/1024.0f) + 1e-6f);
  const float4 gv = *(const float4*)(gamma + tid * 4);
  u16* o = out + (size_t)row * 1024 + tid * 4;
  o[0] = f2bf(xv.x * r * gv.x);
  o[1] = f2bf(xv.y * r * gv.y);
  o[2] = f2bf(xv.z * r * gv.z);
  o[3] = f2bf(xv.w * r * gv.w);
}

// ---------------- 128x128 m97-style bf16 GEMM: C = A(MxK) * Bt(NxK)^T ----------------
// EPI: 0 ->bf16, 1 +bias->bf16, 2 +bias,relu->bf16, 3 +bias,+resid->fp32,
//      5 ->bf16 with scale applied only to cols < 1024 (QKV fused)
template<int EPI>
__global__ __launch_bounds__(256) void gemm128_kernel(
    const u16* __restrict__ A, int lda,
    const u16* __restrict__ Bt,
    const float* __restrict__ bias,
    const float* __restrict__ resid,
    u16* __restrict__ outb, float* __restrict__ outf,
    int N, int K, float scale)
{
  __shared__ __align__(16) u16 As[128*64];
  __shared__ __align__(16) u16 Bs[128*64];
  int tid = threadIdx.x;
  int wid = tid >> 6, lane = tid & 63;
  int fr = lane & 15, fq = lane >> 4;
  int wr = wid >> 1, wc = wid & 1;
  int m0 = blockIdx.x * 128, n0 = blockIdx.y * 128;
  int srow = lane >> 3;            // 0..7 (row within wave's 8-row chunk)
  int scol = (lane & 7) * 8;       // u16 col
  f32x4 acc[4][4] = {};

  const u16* Abase = A  + (size_t)m0 * lda;
  const u16* Bbase = Bt + (size_t)n0 * K;

  for (int k0 = 0; k0 < K; k0 += 64){
    #pragma unroll
    for (int i = 0; i < 4; ++i){
      int r = i*32 + wid*8;
      GLOAD16(Abase + (size_t)(r + srow) * lda + k0 + scol, &As[r * 64]);
      GLOAD16(Bbase + (size_t)(r + srow) * K   + k0 + scol, &Bs[r * 64]);
    }
    __syncthreads();
    #pragma unroll
    for (int ks = 0; ks < 2; ++ks){
      bf16x8 av[4], bv[4];
      #pragma unroll
      for (int mi = 0; mi < 4; ++mi)
        av[mi] = *(const bf16x8*)&As[(wr*64 + mi*16 + fr)*64 + ks*32 + fq*8];
      #pragma unroll
      for (int ni = 0; ni < 4; ++ni)
        bv[ni] = *(const bf16x8*)&Bs[(wc*64 + ni*16 + fr)*64 + ks*32 + fq*8];
      #pragma unroll
      for (int mi = 0; mi < 4; ++mi)
        #pragma unroll
        for (int ni = 0; ni < 4; ++ni)
          acc[mi][ni] = __builtin_amdgcn_mfma_f32_16x16x32_bf16(av[mi], bv[ni], acc[mi][ni], 0, 0, 0);
    }
    __syncthreads();
  }
  // D layout: row = fq*4 + j, col = fr
  #pragma unroll
  for (int ni = 0; ni < 4; ++ni){
    int col = n0 + wc*64 + ni*16 + fr;
    float bvv = (EPI >= 1 && EPI <= 3) ? bias[col] : 0.0f;
    float scl = (EPI == 5) ? ((col < 1024) ? scale : 1.0f) : scale;
    #pragma unroll
    for (int mi = 0; mi < 4; ++mi){
      #pragma unroll
      for (int j = 0; j < 4; ++j){
        int row = m0 + wr*64 + mi*16 + fq*4 + j;
        float vv = acc[mi][ni][j] * scl + bvv;
        if (EPI == 2) vv = fmaxf(vv, 0.0f);
        size_t idx = (size_t)row * N + col;
        if (EPI == 3) outf[idx] = vv + resid[idx];
        else          outb[idx] = f2bf(vv);
      }
    }
  }
}

// ---------------- fused flash attention ----------------
// qkv: (B*S, 3072) bf16 (q cols 0..1023 pre-scaled by 0.125*log2e, k cols 1024.., v cols 2048..)
// Vt: (1024, 8192) bf16 = V^T per (h*64+d, b*1024+s). ctx out: (B*S, 1024) bf16.
__global__ __launch_bounds__(256) void attn_kernel(
    const u16* __restrict__ qkv, const u16* __restrict__ Vt,
    const int* __restrict__ mask, u16* __restrict__ ctx)
{
  __shared__ __align__(16) u16 Ks [64][LDSPAD];
  __shared__ __align__(16) u16 Vts[64][LDSPAD];
  __shared__ __align__(16) u16 Ps [64][LDSPAD];
  int tid = threadIdx.x;
  int wid = tid >> 6, lane = tid & 63;
  int fr = lane & 15, fq = lane >> 4;
  int q0 = blockIdx.x * 64;
  int bh = blockIdx.y;
  int b = bh >> 4, h = bh & 15;
  int srow = tid >> 2, scol = (tid & 3) * 8;

  const u16* qb  = qkv + (size_t)b * 1024 * 3072 + h * 64;          // + s*3072 + d
  const u16* kb  = qb + 1024;
  const u16* vtb = Vt + (size_t)(h * 64) * 8192 + b * 1024;         // + d*8192 + s

  bf16x8 qf[2];
  {
    const u16* qp = qb + (size_t)(q0 + wid*16 + fr) * 3072 + fq * 8;
    qf[0] = *(const bf16x8*)(qp);
    qf[1] = *(const bf16x8*)(qp + 32);
  }
  f32x4 acc_o[4];
  #pragma unroll
  for (int i = 0; i < 4; ++i) acc_o[i] = (f32x4){0.f, 0.f, 0.f, 0.f};
  float mrow[4], lrow[4];
  #pragma unroll
  for (int j = 0; j < 4; ++j){ mrow[j] = -1e30f; lrow[j] = 0.f; }

  for (int t = 0; t < 16; ++t){
    int kv0 = t * 64;
    __syncthreads();
    {
      const u16* kp = kb + (size_t)(kv0 + srow) * 3072 + scol;
      *(bf16x8*)&Ks[srow][scol]      = *(const bf16x8*)(kp);
      *(bf16x8*)&Ks[srow][scol + 32] = *(const bf16x8*)(kp + 32);
      const u16* vp = vtb + (size_t)srow * 8192 + kv0 + scol;
      *(bf16x8*)&Vts[srow][scol]      = *(const bf16x8*)(vp);
      *(bf16x8*)&Vts[srow][scol + 32] = *(const bf16x8*)(vp + 32);
    }
    __syncthreads();

    f32x4 sc[4];
    #pragma unroll
    for (int nt = 0; nt < 4; ++nt) sc[nt] = (f32x4){0.f, 0.f, 0.f, 0.f};
    #pragma unroll
    for (int ks = 0; ks < 2; ++ks){
      #pragma unroll
      for (int nt = 0; nt < 4; ++nt){
        bf16x8 bv = *(const bf16x8*)&Ks[nt*16 + fr][ks*32 + fq*8];
        sc[nt] = __builtin_amdgcn_mfma_f32_16x16x32_bf16(qf[ks], bv, sc[nt], 0, 0, 0);
      }
    }
    float mvals[4];
    #pragma unroll
    for (int nt = 0; nt < 4; ++nt)
      mvals[nt] = (mask[b * 1024 + kv0 + nt*16 + fr] == 0) ? -1e9f : 0.f;

    float pj[4][4];   // [nt][j]
    #pragma unroll
    for (int j = 0; j < 4; ++j){
      float rmax = -1e30f;
      #pragma unroll
      for (int nt = 0; nt < 4; ++nt){
        float s = sc[nt][j] + mvals[nt];
        pj[nt][j] = s;
        rmax = fmaxf(rmax, s);
      }
      rmax = fmaxf(rmax, __shfl_xor(rmax, 1));
      rmax = fmaxf(rmax, __shfl_xor(rmax, 2));
      rmax = fmaxf(rmax, __shfl_xor(rmax, 4));
      rmax = fmaxf(rmax, __shfl_xor(rmax, 8));
      float mnew = fmaxf(mrow[j], rmax);
      float corr = exp2f(mrow[j] - mnew);
      float rsum = 0.f;
      #pragma unroll
      for (int nt = 0; nt < 4; ++nt){
        float p = exp2f(pj[nt][j] - mnew);
        pj[nt][j] = p;
        rsum += p;
      }
      rsum += __shfl_xor(rsum, 1);
      rsum += __shfl_xor(rsum, 2);
      rsum += __shfl_xor(rsum, 4);
      rsum += __shfl_xor(rsum, 8);
      lrow[j] = lrow[j] * corr + rsum;
      mrow[j] = mnew;
      #pragma unroll
      for (int nt = 0; nt < 4; ++nt) acc_o[nt][j] *= corr;
    }
    #pragma unroll
    for (int j = 0; j < 4; ++j)
      #pragma unroll
      for (int nt = 0; nt < 4; ++nt)
        Ps[wid*16 + fq*4 + j][nt*16 + fr] = f2bf(pj[nt][j]);
    __syncthreads();
    // PV: B-fragment rows are V^T rows (d), contiguous k
    #pragma unroll
    for (int ks = 0; ks < 2; ++ks){
      bf16x8 af = *(const bf16x8*)&Ps[wid*16 + fr][ks*32 + fq*8];
      #pragma unroll
      for (int nt = 0; nt < 4; ++nt){
        bf16x8 bv = *(const bf16x8*)&Vts[nt*16 + fr][ks*32 + fq*8];
        acc_o[nt] = __builtin_amdgcn_mfma_f32_16x16x32_bf16(af, bv, acc_o[nt], 0, 0, 0);
      }
    }
  }
  #pragma unroll
  for (int nt = 0; nt < 4; ++nt)
    #pragma unroll
    for (int j = 0; j < 4; ++j){
      float o = acc_o[nt][j] / lrow[j];
      ctx[((size_t)b * 1024 + q0 + wid*16 + fq*4 + j) * 1024 + h*64 + nt*16 + fr] = f2bf(o);
    }
}

// ---------------- depthwise dilated conv (K=4, dil=2, pad 3) + gate, in-place over sec ----------------
__global__ __launch_bounds__(256) void convgate_kernel(
    const u16* __restrict__ f, const float* __restrict__ cw,
    const float* __restrict__ cb, u16* __restrict__ sec_inout)
{
  size_t gid = (size_t)blockIdx.x * blockDim.x + threadIdx.x;  // 2M threads, 8 ch each
  int c0 = (int)(gid & 255) * 8;
  int t  = (int)((gid >> 8) & 1023);
  int b  = (int)(gid >> 18);
  const u16* fb = f + ((size_t)b * 1024) * 2048;
  float acc[8];
  #pragma unroll
  for (int e = 0; e < 8; ++e) acc[e] = cb[c0 + e];
  #pragma unroll
  for (int j = 0; j < 4; ++j){
    int tt = t - 3 + 2 * j;
    if (tt >= 0 && tt < 1024){
      s16x8 fv = *(const s16x8*)(fb + (size_t)tt * 2048 + c0);
      #pragma unroll
      for (int e = 0; e < 8; ++e) acc[e] += bf2f((u16)fv[e]) * cw[(c0 + e) * 4 + j];
    }
  }
  u16* sp = sec_inout + (((size_t)b * 1024 + t) * 2048 + c0);
  s16x8 sv = *(const s16x8*)sp;
  s16x8 ov;
  #pragma unroll
  for (int e = 0; e < 8; ++e) ov[e] = (short)f2bf(acc[e] * bf2f((u16)sv[e]));
  *(s16x8*)sp = ov;
}

// ---------------- host launch ----------------
extern "C" void kernel_launch(void* const* d_in, const int* in_sizes, int n_in,
                              void* d_out, int out_size, void* d_ws, size_t ws_size,
                              hipStream_t stream)
{
  const float* x     = (const float*)d_in[0];
  const int*   mask  = (const int*)  d_in[1];
  const float* gamma = (const float*)d_in[2];
  const float* wq    = (const float*)d_in[3];
  const float* wk    = (const float*)d_in[4];
  const float* wv    = (const float*)d_in[5];
  const float* wo    = (const float*)d_in[6];
  const float* w1    = (const float*)d_in[7];
  const float* b1    = (const float*)d_in[8];
  const float* cw    = (const float*)d_in[9];
  const float* cb    = (const float*)d_in[10];
  const float* w2    = (const float*)d_in[11];
  const float* b2    = (const float*)d_in[12];
  const float* wp    = (const float*)d_in[13];
  const float* bp    = (const float*)d_in[14];
  float* out = (float*)d_out;

  char* p = (char*)d_ws;
  auto alloc = [&](size_t bytes){ char* r = p; p += (bytes + 255) & ~(size_t)255; return r; };
  u16* wqkvT = (u16*)alloc((size_t)3072*1024*2);  // wq^T | wk^T | wv^T contiguous
  u16* woT   = (u16*)alloc((size_t)1024*1024*2);
  u16* w1T   = (u16*)alloc((size_t)2048*512*2);
  u16* w2T   = (u16*)alloc((size_t)2048*512*2);
  u16* wpT   = (u16*)alloc((size_t)1024*2048*2);
  u16* nrm   = (u16*)alloc((size_t)8192*1024*2);   // later: attn ctx
  u16* qkv   = (u16*)alloc((size_t)8192*3072*2);   // later: [0:16MB] ao, [16:48MB] f
  u16* sec   = (u16*)alloc((size_t)8192*2048*2);   // first 16MB doubles as Vt before w2 GEMM
  u16* Vt  = sec;
  u16* ao  = qkv;
  u16* fبuf = qkv + (size_t)8192*1024;
  u16* fbuf = fبuf;
  (void)ws_size; (void)in_sizes; (void)n_in; (void)out_size;

  const float QSCALE = 0.125f * 1.44269504088896340736f;  // 1/sqrt(64) * log2(e)

  dim3 tb32(32, 8);
  wtrans_kernel<<<dim3(32, 32), tb32, 0, stream>>>(wq, wqkvT,                     1024, 1024);
  wtrans_kernel<<<dim3(32, 32), tb32, 0, stream>>>(wk, wqkvT + (size_t)1024*1024, 1024, 1024);
  wtrans_kernel<<<dim3(32, 32), tb32, 0, stream>>>(wv, wqkvT + (size_t)2048*1024, 1024, 1024);
  wtrans_kernel<<<dim3(32, 32), tb32, 0, stream>>>(wo, woT, 1024, 1024);
  wtrans_kernel<<<dim3(64, 16), tb32, 0, stream>>>(w1, w1T, 512, 2048);
  wtrans_kernel<<<dim3(64, 16), tb32, 0, stream>>>(w2, w2T, 512, 2048);
  wtrans_kernel<<<dim3(32, 64), tb32, 0, stream>>>(wp, wpT, 2048, 1024);

  rmsnorm_kernel<<<8192, 256, 0, stream>>>(x, gamma, nrm);

  // fused QKV: (8192x1024) @ (1024x3072) -> qkv, Q cols scaled
  gemm128_kernel<5><<<dim3(64, 24), 256, 0, stream>>>(nrm, 1024, wqkvT, nullptr, nullptr, qkv, nullptr, 3072, 1024, QSCALE);

  // V^T: rows 0..8191 of qkv cols 2048..3071 -> Vt (1024 x 8192)
  btrans_kernel<<<dim3(32, 256), tb32, 0, stream>>>(qkv, 3072, 2048, Vt, 8192, 1024);

  attn_kernel<<<dim3(16, 128), 256, 0, stream>>>(qkv, Vt, mask, nrm);

  // out proj: ctx(nrm) @ wo -> ao
  gemm128_kernel<0><<<dim3(64, 8), 256, 0, stream>>>(nrm, 1024, woT, nullptr, nullptr, ao, nullptr, 1024, 1024, 1.0f);

  // f = ao[:, :512] @ w1 + b1 ; sec = relu(ao[:, 512:] @ w2 + b2)
  gemm128_kernel<1><<<dim3(64, 16), 256, 0, stream>>>(ao,       1024, w1T, b1, nullptr, fbuf, nullptr, 2048, 512, 1.0f);
  gemm128_kernel<2><<<dim3(64, 16), 256, 0, stream>>>(ao + 512, 1024, w2T, b2, nullptr, sec,  nullptr, 2048, 512, 1.0f);

  convgate_kernel<<<8192, 256, 0, stream>>>(fbuf, cw, cb, sec);

  // out = x + gated @ wp + bp
  gemm128_kernel<3><<<dim3(64, 8), 256, 0, stream>>>(sec, 2048, wpT, bp, x, nullptr, out, 1024, 2048, 1.0f);
}

// Round 3
// 464.560 us; speedup vs baseline: 1.3933x; 1.1109x over previous
//
#include <hip/hip_runtime.h>

typedef unsigned short u16;
typedef __bf16 bf16x8 __attribute__((ext_vector_type(8)));
typedef short  s16x8  __attribute__((ext_vector_type(8)));
typedef float  f32x4  __attribute__((ext_vector_type(4)));

#define LDSPAD 72   // 64 + 8 bf16 pad (P^T tile)

// async global->LDS, 16B per lane, LDS dest = wave-uniform base + lane*16
#define GLOAD16(gp, lp) __builtin_amdgcn_global_load_lds( \
  (__attribute__((address_space(1))) unsigned int*)(unsigned long long)(const void*)(gp), \
  (__attribute__((address_space(3))) unsigned int*)(lp), 16, 0, 0)

static __device__ __forceinline__ u16 f2bf(float f){
  union { float f; unsigned int u; } v; v.f = f;
  unsigned int r = v.u + 0x7fffu + ((v.u >> 16) & 1u);
  return (u16)(r >> 16);
}
static __device__ __forceinline__ float bf2f(u16 u){
  union { unsigned int u; float f; } v; v.u = ((unsigned int)u) << 16; return v.f;
}
static __device__ __forceinline__ unsigned fbits(float f){
  union { float f; unsigned u; } v; v.f = f; return v.u;
}

// ---------------- weight transpose + fp32 -> bf16 (out = in^T) ----------------
__global__ __launch_bounds__(256) void wtrans_kernel(const float* __restrict__ in,
                                                     u16* __restrict__ out, int K, int N){
  __shared__ float tile[32][33];
  int n0 = blockIdx.x * 32, k0 = blockIdx.y * 32;
  int tx = threadIdx.x, ty = threadIdx.y;     // block (32, 8)
  #pragma unroll
  for (int i = 0; i < 4; ++i)
    tile[ty + i*8][tx] = in[(size_t)(k0 + ty + i*8) * N + n0 + tx];
  __syncthreads();
  #pragma unroll
  for (int i = 0; i < 4; ++i)
    out[(size_t)(n0 + ty + i*8) * K + k0 + tx] = f2bf(tile[tx][ty + i*8]);
}

// ---------------- bf16 transpose (for V^T): in R x C -> out C x R ----------------
__global__ __launch_bounds__(256) void btrans_kernel(const u16* __restrict__ in, int istride, int ioff,
                                                     u16* __restrict__ out, int R, int C){
  __shared__ u16 tile[32][33];
  int c0 = blockIdx.x * 32, r0 = blockIdx.y * 32;
  int tx = threadIdx.x, ty = threadIdx.y;     // block (32, 8)
  #pragma unroll
  for (int i = 0; i < 4; ++i)
    tile[ty + i*8][tx] = in[(size_t)(r0 + ty + i*8) * istride + ioff + c0 + tx];
  __syncthreads();
  #pragma unroll
  for (int i = 0; i < 4; ++i)
    out[(size_t)(c0 + ty + i*8) * R + r0 + tx] = tile[tx][ty + i*8];
}

// ---------------- RMSNorm: fp32 in -> bf16 out ----------------
__global__ __launch_bounds__(256) void rmsnorm_kernel(const float* __restrict__ x,
                                                      const float* __restrict__ gamma,
                                                      u16* __restrict__ out){
  int row = blockIdx.x;                        // 8192 rows, D=1024
  const float* xr = x + (size_t)row * 1024;
  int tid = threadIdx.x;
  float4 xv = *(const float4*)(xr + tid * 4);
  float ss = xv.x*xv.x + xv.y*xv.y + xv.z*xv.z + xv.w*xv.w;
  #pragma unroll
  for (int off = 1; off < 64; off <<= 1) ss += __shfl_xor(ss, off);
  __shared__ float wsum[4];
  if ((tid & 63) == 0) wsum[tid >> 6] = ss;
  __syncthreads();
  float tot = wsum[0] + wsum[1] + wsum[2] + wsum[3];
  float r = rsqrtf(tot * (1.0f/1024.0f) + 1e-6f);
  const float4 gv = *(const float4*)(gamma + tid * 4);
  u16* o = out + (size_t)row * 1024 + tid * 4;
  o[0] = f2bf(xv.x * r * gv.x);
  o[1] = f2bf(xv.y * r * gv.y);
  o[2] = f2bf(xv.z * r * gv.z);
  o[3] = f2bf(xv.w * r * gv.w);
}

// ---------------- 128x128 m97-style bf16 GEMM: C = A(MxK) * Bt(NxK)^T ----------------
// EPI: 0 ->bf16, 1 +bias->bf16, 2 +bias,relu->bf16, 3 +bias,+resid->fp32,
//      5 ->bf16 with scale applied only to cols < 1024 (QKV fused)
template<int EPI>
__global__ __launch_bounds__(256) void gemm128_kernel(
    const u16* __restrict__ A, int lda,
    const u16* __restrict__ Bt,
    const float* __restrict__ bias,
    const float* __restrict__ resid,
    u16* __restrict__ outb, float* __restrict__ outf,
    int N, int K, float scale)
{
  __shared__ __align__(16) u16 As[128*64];
  __shared__ __align__(16) u16 Bs[128*64];
  int tid = threadIdx.x;
  int wid = tid >> 6, lane = tid & 63;
  int fr = lane & 15, fq = lane >> 4;
  int wr = wid >> 1, wc = wid & 1;
  int m0 = blockIdx.x * 128, n0 = blockIdx.y * 128;
  int srow = lane >> 3;            // 0..7 (row within wave's 8-row chunk)
  int scol = (lane & 7) * 8;       // u16 col
  f32x4 acc[4][4] = {};

  const u16* Abase = A  + (size_t)m0 * lda;
  const u16* Bbase = Bt + (size_t)n0 * K;

  for (int k0 = 0; k0 < K; k0 += 64){
    #pragma unroll
    for (int i = 0; i < 4; ++i){
      int r = i*32 + wid*8;
      GLOAD16(Abase + (size_t)(r + srow) * lda + k0 + scol, &As[r * 64]);
      GLOAD16(Bbase + (size_t)(r + srow) * K   + k0 + scol, &Bs[r * 64]);
    }
    __syncthreads();
    #pragma unroll
    for (int ks = 0; ks < 2; ++ks){
      bf16x8 av[4], bv[4];
      #pragma unroll
      for (int mi = 0; mi < 4; ++mi)
        av[mi] = *(const bf16x8*)&As[(wr*64 + mi*16 + fr)*64 + ks*32 + fq*8];
      #pragma unroll
      for (int ni = 0; ni < 4; ++ni)
        bv[ni] = *(const bf16x8*)&Bs[(wc*64 + ni*16 + fr)*64 + ks*32 + fq*8];
      #pragma unroll
      for (int mi = 0; mi < 4; ++mi)
        #pragma unroll
        for (int ni = 0; ni < 4; ++ni)
          acc[mi][ni] = __builtin_amdgcn_mfma_f32_16x16x32_bf16(av[mi], bv[ni], acc[mi][ni], 0, 0, 0);
    }
    __syncthreads();
  }
  // D layout: row = fq*4 + j, col = fr
  #pragma unroll
  for (int ni = 0; ni < 4; ++ni){
    int col = n0 + wc*64 + ni*16 + fr;
    float bvv = (EPI >= 1 && EPI <= 3) ? bias[col] : 0.0f;
    float scl = (EPI == 5) ? ((col < 1024) ? scale : 1.0f) : scale;
    #pragma unroll
    for (int mi = 0; mi < 4; ++mi){
      #pragma unroll
      for (int j = 0; j < 4; ++j){
        int row = m0 + wr*64 + mi*16 + fq*4 + j;
        float vv = acc[mi][ni][j] * scl + bvv;
        if (EPI == 2) vv = fmaxf(vv, 0.0f);
        size_t idx = (size_t)row * N + col;
        if (EPI == 3) outf[idx] = vv + resid[idx];
        else          outb[idx] = f2bf(vv);
      }
    }
  }
}

// ---------------- fused flash attention (swapped-operand, in-lane softmax) ----------------
// qkv: (B*S, 3072) bf16, Q cols pre-scaled by 0.125*log2e. Vt: (1024, 8192) = V^T.
// ctx out: (B*S, 1024) bf16.
// S^T = mfma(K, Q): lane (fq,fr) holds S^T[k=nt*16+fq*4+j][q=wid*16+fr] -> softmax in-lane.
// O^T = mfma(V^T, P^T): P^T via per-wave LDS (no barrier).
// K/V LDS: linear [64][64] u16 with 16B-chunk XOR swizzle (chunk ^= row&7), staged by
// global_load_lds with pre-swizzled SOURCE address (rule #21); reads apply same XOR.
__global__ __launch_bounds__(256) void attn_kernel(
    const u16* __restrict__ qkv, const u16* __restrict__ Vt,
    const int* __restrict__ mask, u16* __restrict__ ctx)
{
  __shared__ __align__(16) u16 Ks[64*64];
  __shared__ __align__(16) u16 Vs[64*64];
  __shared__ __align__(16) u16 Ps[64][LDSPAD];
  int tid = threadIdx.x;
  int wid = tid >> 6, lane = tid & 63;
  int fr = lane & 15, fq = lane >> 4;
  int q0 = blockIdx.x * 64;
  int bh = blockIdx.y;
  int b = bh >> 4, h = bh & 15;

  const u16* qb  = qkv + (size_t)b * 1024 * 3072 + h * 64;          // + s*3072 + d
  const u16* kb  = qb + 1024;
  const u16* vtb = Vt + (size_t)(h * 64) * 8192 + b * 1024;         // + d*8192 + s

  // staging geometry: lane l -> LDS row (wbase + i*8 + (l>>3)), chunk (l&7); source chunk XOR'd
  int lrow = lane >> 3;                   // 0..7
  int cs   = (lane & 7) ^ lrow;           // pre-swizzled source 16B-chunk
  int wbase = wid * 16;

  bf16x8 qf[2];
  {
    const u16* qp = qb + (size_t)(q0 + wid*16 + fr) * 3072 + fq * 8;
    qf[0] = *(const bf16x8*)(qp);
    qf[1] = *(const bf16x8*)(qp + 32);
  }
  f32x4 acc[4];   // O^T: acc[nt][j] = O[d = nt*16+fq*4+j][q = wid*16+fr]
  #pragma unroll
  for (int i = 0; i < 4; ++i) acc[i] = (f32x4){0.f, 0.f, 0.f, 0.f};
  float m = -1e30f, lsum = 0.f;
  int c7 = fr & 7;   // read-side row XOR

  for (int t = 0; t < 16; ++t){
    int kv0 = t * 64;
    __syncthreads();
    #pragma unroll
    for (int i = 0; i < 2; ++i){
      int r = wbase + i*8 + lrow;
      GLOAD16(kb  + (size_t)(kv0 + r) * 3072 + cs * 8, &Ks[(wbase + i*8) * 64]);
      GLOAD16(vtb + (size_t)r * 8192 + kv0 + cs * 8,   &Vs[(wbase + i*8) * 64]);
    }
    __syncthreads();

    // QK^T (swapped): sc[nt][j] = S^T[k = nt*16+fq*4+j][q = wid*16+fr]
    f32x4 sc[4];
    #pragma unroll
    for (int nt = 0; nt < 4; ++nt) sc[nt] = (f32x4){0.f, 0.f, 0.f, 0.f};
    __builtin_amdgcn_s_setprio(1);
    #pragma unroll
    for (int ks = 0; ks < 2; ++ks){
      #pragma unroll
      for (int nt = 0; nt < 4; ++nt){
        bf16x8 kv = *(const bf16x8*)&Ks[(nt*16 + fr)*64 + (((ks*4 + fq) ^ c7) * 8)];
        sc[nt] = __builtin_amdgcn_mfma_f32_16x16x32_bf16(kv, qf[ks], sc[nt], 0, 0, 0);
      }
    }
    __builtin_amdgcn_s_setprio(0);

    // mask (k rows per lane: kv0 + nt*16 + fq*4 + j)
    #pragma unroll
    for (int nt = 0; nt < 4; ++nt){
      int4 mv = *(const int4*)&mask[b * 1024 + kv0 + nt*16 + fq*4];
      int mvals[4] = {mv.x, mv.y, mv.z, mv.w};
      #pragma unroll
      for (int j = 0; j < 4; ++j)
        sc[nt][j] = mvals[j] ? sc[nt][j] : -1e9f;
    }

    // in-lane softmax (log2 domain)
    float pmax = -1e30f;
    #pragma unroll
    for (int nt = 0; nt < 4; ++nt)
      #pragma unroll
      for (int j = 0; j < 4; ++j)
        pmax = fmaxf(pmax, sc[nt][j]);
    pmax = fmaxf(pmax, __shfl_xor(pmax, 16));
    pmax = fmaxf(pmax, __shfl_xor(pmax, 32));
    if (!__all(pmax <= m + 8.0f)){            // defer-max (T13)
      float mnew = fmaxf(m, pmax);
      float corr = exp2f(m - mnew);
      #pragma unroll
      for (int nt = 0; nt < 4; ++nt)
        #pragma unroll
        for (int j = 0; j < 4; ++j)
          acc[nt][j] *= corr;
      lsum *= corr;
      m = mnew;
    }
    float p[4][4];
    float ls = 0.f;
    #pragma unroll
    for (int nt = 0; nt < 4; ++nt)
      #pragma unroll
      for (int j = 0; j < 4; ++j){
        float pv = exp2f(sc[nt][j] - m);
        p[nt][j] = pv;
        ls += pv;
      }
    lsum += ls;

    // P^T -> per-wave LDS rows (truncate-to-bf16 pairs via v_perm), no barrier needed
    #pragma unroll
    for (int nt = 0; nt < 4; ++nt){
      unsigned d0 = __builtin_amdgcn_perm(fbits(p[nt][1]), fbits(p[nt][0]), 0x07060302u);
      unsigned d1 = __builtin_amdgcn_perm(fbits(p[nt][3]), fbits(p[nt][2]), 0x07060302u);
      *(unsigned*)&Ps[wid*16 + fr][nt*16 + fq*4]     = d0;
      *(unsigned*)&Ps[wid*16 + fr][nt*16 + fq*4 + 2] = d1;
    }

    // PV (swapped): acc[nt] += mfma(V^T frag, P^T frag)
    __builtin_amdgcn_s_setprio(1);
    #pragma unroll
    for (int ks = 0; ks < 2; ++ks){
      bf16x8 pb = *(const bf16x8*)&Ps[wid*16 + fr][ks*32 + fq*8];
      #pragma unroll
      for (int nt = 0; nt < 4; ++nt){
        bf16x8 vv = *(const bf16x8*)&Vs[(nt*16 + fr)*64 + (((ks*4 + fq) ^ c7) * 8)];
        acc[nt] = __builtin_amdgcn_mfma_f32_16x16x32_bf16(vv, pb, acc[nt], 0, 0, 0);
      }
    }
    __builtin_amdgcn_s_setprio(0);
  }

  lsum += __shfl_xor(lsum, 16);
  lsum += __shfl_xor(lsum, 32);
  float invl = 1.0f / lsum;

  // O^T write-back: d = nt*16+fq*4+j, q = wid*16+fr
  size_t rowbase = ((size_t)b * 1024 + q0 + wid*16 + fr) * 1024 + h * 64;
  #pragma unroll
  for (int nt = 0; nt < 4; ++nt){
    unsigned lo = (unsigned)f2bf(acc[nt][0] * invl) | ((unsigned)f2bf(acc[nt][1] * invl) << 16);
    unsigned hi = (unsigned)f2bf(acc[nt][2] * invl) | ((unsigned)f2bf(acc[nt][3] * invl) << 16);
    uint2 pk; pk.x = lo; pk.y = hi;
    *(uint2*)&ctx[rowbase + nt*16 + fq*4] = pk;
  }
}

// ---------------- depthwise dilated conv (K=4, dil=2, pad 3) + gate, in-place over sec ----------------
__global__ __launch_bounds__(256) void convgate_kernel(
    const u16* __restrict__ f, const float* __restrict__ cw,
    const float* __restrict__ cb, u16* __restrict__ sec_inout)
{
  size_t gid = (size_t)blockIdx.x * blockDim.x + threadIdx.x;  // 2M threads, 8 ch each
  int c0 = (int)(gid & 255) * 8;
  int t  = (int)((gid >> 8) & 1023);
  int b  = (int)(gid >> 18);
  const u16* fb = f + ((size_t)b * 1024) * 2048;
  float acc[8];
  #pragma unroll
  for (int e = 0; e < 8; ++e) acc[e] = cb[c0 + e];
  #pragma unroll
  for (int j = 0; j < 4; ++j){
    int tt = t - 3 + 2 * j;
    if (tt >= 0 && tt < 1024){
      s16x8 fv = *(const s16x8*)(fb + (size_t)tt * 2048 + c0);
      #pragma unroll
      for (int e = 0; e < 8; ++e) acc[e] += bf2f((u16)fv[e]) * cw[(c0 + e) * 4 + j];
    }
  }
  u16* sp = sec_inout + (((size_t)b * 1024 + t) * 2048 + c0);
  s16x8 sv = *(const s16x8*)sp;
  s16x8 ov;
  #pragma unroll
  for (int e = 0; e < 8; ++e) ov[e] = (short)f2bf(acc[e] * bf2f((u16)sv[e]));
  *(s16x8*)sp = ov;
}

// ---------------- host launch ----------------
extern "C" void kernel_launch(void* const* d_in, const int* in_sizes, int n_in,
                              void* d_out, int out_size, void* d_ws, size_t ws_size,
                              hipStream_t stream)
{
  const float* x     = (const float*)d_in[0];
  const int*   mask  = (const int*)  d_in[1];
  const float* gamma = (const float*)d_in[2];
  const float* wq    = (const float*)d_in[3];
  const float* wk    = (const float*)d_in[4];
  const float* wv    = (const float*)d_in[5];
  const float* wo    = (const float*)d_in[6];
  const float* w1    = (const float*)d_in[7];
  const float* b1    = (const float*)d_in[8];
  const float* cw    = (const float*)d_in[9];
  const float* cb    = (const float*)d_in[10];
  const float* w2    = (const float*)d_in[11];
  const float* b2    = (const float*)d_in[12];
  const float* wp    = (const float*)d_in[13];
  const float* bp    = (const float*)d_in[14];
  float* out = (float*)d_out;

  char* p = (char*)d_ws;
  auto alloc = [&](size_t bytes){ char* r = p; p += (bytes + 255) & ~(size_t)255; return r; };
  u16* wqkvT = (u16*)alloc((size_t)3072*1024*2);  // wq^T | wk^T | wv^T contiguous
  u16* woT   = (u16*)alloc((size_t)1024*1024*2);
  u16* w1T   = (u16*)alloc((size_t)2048*512*2);
  u16* w2T   = (u16*)alloc((size_t)2048*512*2);
  u16* wpT   = (u16*)alloc((size_t)1024*2048*2);
  u16* nrm   = (u16*)alloc((size_t)8192*1024*2);   // later: attn ctx
  u16* qkv   = (u16*)alloc((size_t)8192*3072*2);   // later: [0:16MB] ao, [16:48MB] f
  u16* sec   = (u16*)alloc((size_t)8192*2048*2);   // first 16MB doubles as Vt before w2 GEMM
  u16* Vt   = sec;
  u16* ao   = qkv;
  u16* fbuf = qkv + (size_t)8192*1024;
  (void)ws_size; (void)in_sizes; (void)n_in; (void)out_size;

  const float QSCALE = 0.125f * 1.44269504088896340736f;  // 1/sqrt(64) * log2(e)

  dim3 tb32(32, 8);
  wtrans_kernel<<<dim3(32, 32), tb32, 0, stream>>>(wq, wqkvT,                     1024, 1024);
  wtrans_kernel<<<dim3(32, 32), tb32, 0, stream>>>(wk, wqkvT + (size_t)1024*1024, 1024, 1024);
  wtrans_kernel<<<dim3(32, 32), tb32, 0, stream>>>(wv, wqkvT + (size_t)2048*1024, 1024, 1024);
  wtrans_kernel<<<dim3(32, 32), tb32, 0, stream>>>(wo, woT, 1024, 1024);
  wtrans_kernel<<<dim3(64, 16), tb32, 0, stream>>>(w1, w1T, 512, 2048);
  wtrans_kernel<<<dim3(64, 16), tb32, 0, stream>>>(w2, w2T, 512, 2048);
  wtrans_kernel<<<dim3(32, 64), tb32, 0, stream>>>(wp, wpT, 2048, 1024);

  rmsnorm_kernel<<<8192, 256, 0, stream>>>(x, gamma, nrm);

  // fused QKV: (8192x1024) @ (1024x3072) -> qkv, Q cols scaled
  gemm128_kernel<5><<<dim3(64, 24), 256, 0, stream>>>(nrm, 1024, wqkvT, nullptr, nullptr, qkv, nullptr, 3072, 1024, QSCALE);

  // V^T: rows 0..8191 of qkv cols 2048..3071 -> Vt (1024 x 8192)
  btrans_kernel<<<dim3(32, 256), tb32, 0, stream>>>(qkv, 3072, 2048, Vt, 8192, 1024);

  attn_kernel<<<dim3(16, 128), 256, 0, stream>>>(qkv, Vt, mask, nrm);

  // out proj: ctx(nrm) @ wo -> ao
  gemm128_kernel<0><<<dim3(64, 8), 256, 0, stream>>>(nrm, 1024, woT, nullptr, nullptr, ao, nullptr, 1024, 1024, 1.0f);

  // f = ao[:, :512] @ w1 + b1 ; sec = relu(ao[:, 512:] @ w2 + b2)
  gemm128_kernel<1><<<dim3(64, 16), 256, 0, stream>>>(ao,       1024, w1T, b1, nullptr, fbuf, nullptr, 2048, 512, 1.0f);
  gemm128_kernel<2><<<dim3(64, 16), 256, 0, stream>>>(ao + 512, 1024, w2T, b2, nullptr, sec,  nullptr, 2048, 512, 1.0f);

  convgate_kernel<<<8192, 256, 0, stream>>>(fbuf, cw, cb, sec);

  // out = x + gated @ wp + bp
  gemm128_kernel<3><<<dim3(64, 8), 256, 0, stream>>>(sec, 2048, wpT, bp, x, nullptr, out, 1024, 2048, 1.0f);
}

// Round 5
// 370.491 us; speedup vs baseline: 1.7471x; 1.2539x over previous
//
#include <hip/hip_runtime.h>

typedef unsigned short u16;
typedef __bf16 bf16x8 __attribute__((ext_vector_type(8)));
typedef short  s16x8  __attribute__((ext_vector_type(8)));
typedef float  f32x4  __attribute__((ext_vector_type(4)));

#define LDSPAD 72   // 64 + 8 bf16 pad (P^T tile)

// async global->LDS, 16B per lane, LDS dest = wave-uniform base + lane*16
#define GLOAD16(gp, lp) __builtin_amdgcn_global_load_lds( \
  (__attribute__((address_space(1))) unsigned int*)(unsigned long long)(const void*)(gp), \
  (__attribute__((address_space(3))) unsigned int*)(lp), 16, 0, 0)

static __device__ __forceinline__ u16 f2bf(float f){
  union { float f; unsigned int u; } v; v.f = f;
  unsigned int r = v.u + 0x7fffu + ((v.u >> 16) & 1u);
  return (u16)(r >> 16);
}
static __device__ __forceinline__ float bf2f(u16 u){
  union { unsigned int u; float f; } v; v.u = ((unsigned int)u) << 16; return v.f;
}
static __device__ __forceinline__ unsigned fbits(float f){
  union { float f; unsigned u; } v; v.f = f; return v.u;
}

// ---------------- weight transpose + fp32 -> bf16 (out = in^T) ----------------
__global__ __launch_bounds__(256) void wtrans_kernel(const float* __restrict__ in,
                                                     u16* __restrict__ out, int K, int N){
  __shared__ float tile[32][33];
  int n0 = blockIdx.x * 32, k0 = blockIdx.y * 32;
  int tx = threadIdx.x, ty = threadIdx.y;     // block (32, 8)
  #pragma unroll
  for (int i = 0; i < 4; ++i)
    tile[ty + i*8][tx] = in[(size_t)(k0 + ty + i*8) * N + n0 + tx];
  __syncthreads();
  #pragma unroll
  for (int i = 0; i < 4; ++i)
    out[(size_t)(n0 + ty + i*8) * K + k0 + tx] = f2bf(tile[tx][ty + i*8]);
}

// ---------------- conv weight transpose: cw (2048,1,4) -> cwT (4,2048) ----------------
__global__ __launch_bounds__(256) void cwtrans_kernel(const float* __restrict__ cw,
                                                      float* __restrict__ cwT){
  int i = blockIdx.x * 256 + threadIdx.x;   // 8192
  int c = i >> 2, j = i & 3;
  cwT[j * 2048 + c] = cw[i];
}

// ---------------- RMSNorm: fp32 in -> bf16 out ----------------
__global__ __launch_bounds__(256) void rmsnorm_kernel(const float* __restrict__ x,
                                                      const float* __restrict__ gamma,
                                                      u16* __restrict__ out){
  int row = blockIdx.x;                        // 8192 rows, D=1024
  const float* xr = x + (size_t)row * 1024;
  int tid = threadIdx.x;
  float4 xv = *(const float4*)(xr + tid * 4);
  float ss = xv.x*xv.x + xv.y*xv.y + xv.z*xv.z + xv.w*xv.w;
  #pragma unroll
  for (int off = 1; off < 64; off <<= 1) ss += __shfl_xor(ss, off);
  __shared__ float wsum[4];
  if ((tid & 63) == 0) wsum[tid >> 6] = ss;
  __syncthreads();
  float tot = wsum[0] + wsum[1] + wsum[2] + wsum[3];
  float r = rsqrtf(tot * (1.0f/1024.0f) + 1e-6f);
  const float4 gv = *(const float4*)(gamma + tid * 4);
  u16* o = out + (size_t)row * 1024 + tid * 4;
  o[0] = f2bf(xv.x * r * gv.x);
  o[1] = f2bf(xv.y * r * gv.y);
  o[2] = f2bf(xv.z * r * gv.z);
  o[3] = f2bf(xv.w * r * gv.w);
}

// ---------------- 128x128 m97-style bf16 GEMM: C = A(MxK) * Bt(NxK)^T ----------------
// EPI: 0 ->bf16, 1 +bias->bf16, 2 +bias,relu->bf16, 3 +bias,+resid->fp32,
//      5 QKV fused: cols<1024 scaled ->outb, cols in [1024,2048) ->outb,
//        cols>=2048 -> vt[(col-2048)*8192 + row] (V^T, packed 8B writes)
template<int EPI>
__global__ __launch_bounds__(256) void gemm128_kernel(
    const u16* __restrict__ A, int lda,
    const u16* __restrict__ Bt,
    const float* __restrict__ bias,
    const float* __restrict__ resid,
    u16* __restrict__ outb, float* __restrict__ outf,
    u16* __restrict__ vt,
    int N, int K, float scale)
{
  __shared__ __align__(16) u16 As[128*64];
  __shared__ __align__(16) u16 Bs[128*64];
  int tid = threadIdx.x;
  int wid = tid >> 6, lane = tid & 63;
  int fr = lane & 15, fq = lane >> 4;
  int wr = wid >> 1, wc = wid & 1;
  int m0 = blockIdx.x * 128, n0 = blockIdx.y * 128;
  int srow = lane >> 3;            // 0..7 (row within wave's 8-row chunk)
  int scol = (lane & 7) * 8;       // u16 col
  f32x4 acc[4][4] = {};

  const u16* Abase = A  + (size_t)m0 * lda;
  const u16* Bbase = Bt + (size_t)n0 * K;

  for (int k0 = 0; k0 < K; k0 += 64){
    #pragma unroll
    for (int i = 0; i < 4; ++i){
      int r = i*32 + wid*8;
      GLOAD16(Abase + (size_t)(r + srow) * lda + k0 + scol, &As[r * 64]);
      GLOAD16(Bbase + (size_t)(r + srow) * K   + k0 + scol, &Bs[r * 64]);
    }
    __syncthreads();
    #pragma unroll
    for (int ks = 0; ks < 2; ++ks){
      bf16x8 av[4], bv[4];
      #pragma unroll
      for (int mi = 0; mi < 4; ++mi)
        av[mi] = *(const bf16x8*)&As[(wr*64 + mi*16 + fr)*64 + ks*32 + fq*8];
      #pragma unroll
      for (int ni = 0; ni < 4; ++ni)
        bv[ni] = *(const bf16x8*)&Bs[(wc*64 + ni*16 + fr)*64 + ks*32 + fq*8];
      #pragma unroll
      for (int mi = 0; mi < 4; ++mi)
        #pragma unroll
        for (int ni = 0; ni < 4; ++ni)
          acc[mi][ni] = __builtin_amdgcn_mfma_f32_16x16x32_bf16(av[mi], bv[ni], acc[mi][ni], 0, 0, 0);
    }
    __syncthreads();
  }
  // D layout: row = fq*4 + j, col = fr
  #pragma unroll
  for (int ni = 0; ni < 4; ++ni){
    int col = n0 + wc*64 + ni*16 + fr;
    float bvv = (EPI >= 1 && EPI <= 3) ? bias[col] : 0.0f;
    float scl = (EPI == 5) ? ((col < 1024) ? scale : 1.0f) : scale;
    #pragma unroll
    for (int mi = 0; mi < 4; ++mi){
      if (EPI == 5 && col >= 2048){
        int row0 = m0 + wr*64 + mi*16 + fq*4;
        uint2 pk;
        pk.x = (unsigned)f2bf(acc[mi][ni][0]) | ((unsigned)f2bf(acc[mi][ni][1]) << 16);
        pk.y = (unsigned)f2bf(acc[mi][ni][2]) | ((unsigned)f2bf(acc[mi][ni][3]) << 16);
        *(uint2*)&vt[(size_t)(col - 2048) * 8192 + row0] = pk;
      } else {
        #pragma unroll
        for (int j = 0; j < 4; ++j){
          int row = m0 + wr*64 + mi*16 + fq*4 + j;
          float vv = acc[mi][ni][j] * scl + bvv;
          if (EPI == 2) vv = fmaxf(vv, 0.0f);
          size_t idx = (size_t)row * N + col;
          if (EPI == 3) outf[idx] = vv + resid[idx];
          else          outb[idx] = f2bf(vv);
        }
      }
    }
  }
}

// ---------------- fused flash attention (swapped-operand, in-lane softmax) ----------------
// qkv: (B*S, 3072) bf16, Q cols pre-scaled by 0.125*log2e. Vt: (1024, 8192) = V^T.
// ctx out: (B*S, 1024) bf16.
__global__ __launch_bounds__(256) void attn_kernel(
    const u16* __restrict__ qkv, const u16* __restrict__ Vt,
    const int* __restrict__ mask, u16* __restrict__ ctx)
{
  __shared__ __align__(16) u16 Ks[64*64];
  __shared__ __align__(16) u16 Vs[64*64];
  __shared__ __align__(16) u16 Ps[64][LDSPAD];
  int tid = threadIdx.x;
  int wid = tid >> 6, lane = tid & 63;
  int fr = lane & 15, fq = lane >> 4;
  int q0 = blockIdx.x * 64;
  int bh = blockIdx.y;
  int b = bh >> 4, h = bh & 15;

  const u16* qb  = qkv + (size_t)b * 1024 * 3072 + h * 64;          // + s*3072 + d
  const u16* kb  = qb + 1024;
  const u16* vtb = Vt + (size_t)(h * 64) * 8192 + b * 1024;         // + d*8192 + s

  int lrow = lane >> 3;                   // 0..7
  int cs   = (lane & 7) ^ lrow;           // pre-swizzled source 16B-chunk
  int wbase = wid * 16;

  bf16x8 qf[2];
  {
    const u16* qp = qb + (size_t)(q0 + wid*16 + fr) * 3072 + fq * 8;
    qf[0] = *(const bf16x8*)(qp);
    qf[1] = *(const bf16x8*)(qp + 32);
  }
  f32x4 acc[4];   // O^T: acc[nt][j] = O[d = nt*16+fq*4+j][q = wid*16+fr]
  #pragma unroll
  for (int i = 0; i < 4; ++i) acc[i] = (f32x4){0.f, 0.f, 0.f, 0.f};
  float m = -1e30f, lsum = 0.f;
  int c7 = fr & 7;   // read-side row XOR

  for (int t = 0; t < 16; ++t){
    int kv0 = t * 64;
    __syncthreads();
    #pragma unroll
    for (int i = 0; i < 2; ++i){
      int r = wbase + i*8 + lrow;
      GLOAD16(kb  + (size_t)(kv0 + r) * 3072 + cs * 8, &Ks[(wbase + i*8) * 64]);
      GLOAD16(vtb + (size_t)r * 8192 + kv0 + cs * 8,   &Vs[(wbase + i*8) * 64]);
    }
    __syncthreads();

    // QK^T (swapped): sc[nt][j] = S^T[k = nt*16+fq*4+j][q = wid*16+fr]
    f32x4 sc[4];
    #pragma unroll
    for (int nt = 0; nt < 4; ++nt) sc[nt] = (f32x4){0.f, 0.f, 0.f, 0.f};
    __builtin_amdgcn_s_setprio(1);
    #pragma unroll
    for (int ks = 0; ks < 2; ++ks){
      #pragma unroll
      for (int nt = 0; nt < 4; ++nt){
        bf16x8 kv = *(const bf16x8*)&Ks[(nt*16 + fr)*64 + (((ks*4 + fq) ^ c7) * 8)];
        sc[nt] = __builtin_amdgcn_mfma_f32_16x16x32_bf16(kv, qf[ks], sc[nt], 0, 0, 0);
      }
    }
    __builtin_amdgcn_s_setprio(0);

    // mask (k rows per lane: kv0 + nt*16 + fq*4 + j)
    #pragma unroll
    for (int nt = 0; nt < 4; ++nt){
      int4 mv = *(const int4*)&mask[b * 1024 + kv0 + nt*16 + fq*4];
      int mvals[4] = {mv.x, mv.y, mv.z, mv.w};
      #pragma unroll
      for (int j = 0; j < 4; ++j)
        sc[nt][j] = mvals[j] ? sc[nt][j] : -1e9f;
    }

    // in-lane softmax (log2 domain)
    float pmax = -1e30f;
    #pragma unroll
    for (int nt = 0; nt < 4; ++nt)
      #pragma unroll
      for (int j = 0; j < 4; ++j)
        pmax = fmaxf(pmax, sc[nt][j]);
    pmax = fmaxf(pmax, __shfl_xor(pmax, 16));
    pmax = fmaxf(pmax, __shfl_xor(pmax, 32));
    if (!__all(pmax <= m + 8.0f)){            // defer-max (T13)
      float mnew = fmaxf(m, pmax);
      float corr = exp2f(m - mnew);
      #pragma unroll
      for (int nt = 0; nt < 4; ++nt)
        #pragma unroll
        for (int j = 0; j < 4; ++j)
          acc[nt][j] *= corr;
      lsum *= corr;
      m = mnew;
    }
    float p[4][4];
    float ls = 0.f;
    #pragma unroll
    for (int nt = 0; nt < 4; ++nt)
      #pragma unroll
      for (int j = 0; j < 4; ++j){
        float pv = exp2f(sc[nt][j] - m);
        p[nt][j] = pv;
        ls += pv;
      }
    lsum += ls;

    // P^T -> per-wave LDS rows (truncate-to-bf16 pairs via v_perm), no barrier needed
    #pragma unroll
    for (int nt = 0; nt < 4; ++nt){
      unsigned d0 = __builtin_amdgcn_perm(fbits(p[nt][1]), fbits(p[nt][0]), 0x07060302u);
      unsigned d1 = __builtin_amdgcn_perm(fbits(p[nt][3]), fbits(p[nt][2]), 0x07060302u);
      *(unsigned*)&Ps[wid*16 + fr][nt*16 + fq*4]     = d0;
      *(unsigned*)&Ps[wid*16 + fr][nt*16 + fq*4 + 2] = d1;
    }

    // PV (swapped): acc[nt] += mfma(V^T frag, P^T frag)
    __builtin_amdgcn_s_setprio(1);
    #pragma unroll
    for (int ks = 0; ks < 2; ++ks){
      bf16x8 pb = *(const bf16x8*)&Ps[wid*16 + fr][ks*32 + fq*8];
      #pragma unroll
      for (int nt = 0; nt < 4; ++nt){
        bf16x8 vv = *(const bf16x8*)&Vs[(nt*16 + fr)*64 + (((ks*4 + fq) ^ c7) * 8)];
        acc[nt] = __builtin_amdgcn_mfma_f32_16x16x32_bf16(vv, pb, acc[nt], 0, 0, 0);
      }
    }
    __builtin_amdgcn_s_setprio(0);
  }

  lsum += __shfl_xor(lsum, 16);
  lsum += __shfl_xor(lsum, 32);
  float invl = 1.0f / lsum;

  // O^T write-back: d = nt*16+fq*4+j, q = wid*16+fr
  size_t rowbase = ((size_t)b * 1024 + q0 + wid*16 + fr) * 1024 + h * 64;
  #pragma unroll
  for (int nt = 0; nt < 4; ++nt){
    unsigned lo = (unsigned)f2bf(acc[nt][0] * invl) | ((unsigned)f2bf(acc[nt][1] * invl) << 16);
    unsigned hi = (unsigned)f2bf(acc[nt][2] * invl) | ((unsigned)f2bf(acc[nt][3] * invl) << 16);
    uint2 pk; pk.x = lo; pk.y = hi;
    *(uint2*)&ctx[rowbase + nt*16 + fq*4] = pk;
  }
}

// ---------------- depthwise dilated conv (K=4, dil=2, pad 3) + gate, in-place over sec ----------------
// cwT: (4, 2048) f32 transposed conv weights -> coalesced vector loads
__global__ __launch_bounds__(256) void convgate_kernel(
    const u16* __restrict__ f, const float* __restrict__ cwT,
    const float* __restrict__ cb, u16* __restrict__ sec_inout)
{
  size_t gid = (size_t)blockIdx.x * blockDim.x + threadIdx.x;  // 2M threads, 8 ch each
  int c0 = (int)(gid & 255) * 8;
  int t  = (int)((gid >> 8) & 1023);
  int b  = (int)(gid >> 18);
  const u16* fb = f + ((size_t)b * 1024) * 2048;

  // coalesced weight/bias loads (lane stride 32B)
  float4 w[4][2];
  #pragma unroll
  for (int j = 0; j < 4; ++j){
    w[j][0] = *(const float4*)&cwT[j*2048 + c0];
    w[j][1] = *(const float4*)&cwT[j*2048 + c0 + 4];
  }
  float4 cb0 = *(const float4*)&cb[c0];
  float4 cb1 = *(const float4*)&cb[c0 + 4];
  float acc[8] = {cb0.x, cb0.y, cb0.z, cb0.w, cb1.x, cb1.y, cb1.z, cb1.w};

  #pragma unroll
  for (int j = 0; j < 4; ++j){
    int tt = t - 3 + 2 * j;
    if (tt >= 0 && tt < 1024){     // block-uniform branch (t is block-uniform)
      s16x8 fv = *(const s16x8*)(fb + (size_t)tt * 2048 + c0);
      const float* wj = (const float*)&w[j][0];
      #pragma unroll
      for (int e = 0; e < 8; ++e) acc[e] += bf2f((u16)fv[e]) * wj[e];
    }
  }
  u16* sp = sec_inout + (((size_t)b * 1024 + t) * 2048 + c0);
  s16x8 sv = *(const s16x8*)sp;
  s16x8 ov;
  #pragma unroll
  for (int e = 0; e < 8; ++e) ov[e] = (short)f2bf(acc[e] * bf2f((u16)sv[e]));
  *(s16x8*)sp = ov;
}

// ---------------- host launch ----------------
extern "C" void kernel_launch(void* const* d_in, const int* in_sizes, int n_in,
                              void* d_out, int out_size, void* d_ws, size_t ws_size,
                              hipStream_t stream)
{
  const float* x     = (const float*)d_in[0];
  const int*   mask  = (const int*)  d_in[1];
  const float* gamma = (const float*)d_in[2];
  const float* wq    = (const float*)d_in[3];
  const float* wk    = (const float*)d_in[4];
  const float* wv    = (const float*)d_in[5];
  const float* wo    = (const float*)d_in[6];
  const float* w1    = (const float*)d_in[7];
  const float* b1    = (const float*)d_in[8];
  const float* cw    = (const float*)d_in[9];
  const float* cb    = (const float*)d_in[10];
  const float* w2    = (const float*)d_in[11];
  const float* b2    = (const float*)d_in[12];
  const float* wp    = (const float*)d_in[13];
  const float* bp    = (const float*)d_in[14];
  float* out = (float*)d_out;

  char* p = (char*)d_ws;
  auto alloc = [&](size_t bytes){ char* r = p; p += (bytes + 255) & ~(size_t)255; return r; };
  u16*   wqkvT = (u16*)alloc((size_t)3072*1024*2);  // wq^T | wk^T | wv^T contiguous
  u16*   woT   = (u16*)alloc((size_t)1024*1024*2);
  u16*   w1T   = (u16*)alloc((size_t)2048*512*2);
  u16*   w2T   = (u16*)alloc((size_t)2048*512*2);
  u16*   wpT   = (u16*)alloc((size_t)1024*2048*2);
  float* cwT   = (float*)alloc((size_t)4*2048*4);
  u16*   nrm   = (u16*)alloc((size_t)8192*1024*2);   // later: attn ctx
  u16*   qkv   = (u16*)alloc((size_t)8192*3072*2);   // later: [0:16MB] ao, [16:48MB] f
  u16*   sec   = (u16*)alloc((size_t)8192*2048*2);   // first 16MB doubles as Vt before w2 GEMM
  u16* Vt   = sec;
  u16* ao   = qkv;
  u16* fbuf = qkv + (size_t)8192*1024;
  (void)ws_size; (void)in_sizes; (void)n_in; (void)out_size;

  const float QSCALE = 0.125f * 1.44269504088896340736f;  // 1/sqrt(64) * log2(e)

  dim3 tb32(32, 8);
  wtrans_kernel<<<dim3(32, 32), tb32, 0, stream>>>(wq, wqkvT,                     1024, 1024);
  wtrans_kernel<<<dim3(32, 32), tb32, 0, stream>>>(wk, wqkvT + (size_t)1024*1024, 1024, 1024);
  wtrans_kernel<<<dim3(32, 32), tb32, 0, stream>>>(wv, wqkvT + (size_t)2048*1024, 1024, 1024);
  wtrans_kernel<<<dim3(32, 32), tb32, 0, stream>>>(wo, woT, 1024, 1024);
  wtrans_kernel<<<dim3(64, 16), tb32, 0, stream>>>(w1, w1T, 512, 2048);
  wtrans_kernel<<<dim3(64, 16), tb32, 0, stream>>>(w2, w2T, 512, 2048);
  wtrans_kernel<<<dim3(32, 64), tb32, 0, stream>>>(wp, wpT, 2048, 1024);
  cwtrans_kernel<<<32, 256, 0, stream>>>(cw, cwT);

  rmsnorm_kernel<<<8192, 256, 0, stream>>>(x, gamma, nrm);

  // fused QKV: (8192x1024) @ (1024x3072) -> qkv (q,k) + Vt (V^T direct)
  gemm128_kernel<5><<<dim3(64, 24), 256, 0, stream>>>(nrm, 1024, wqkvT, nullptr, nullptr, qkv, nullptr, Vt, 3072, 1024, QSCALE);

  attn_kernel<<<dim3(16, 128), 256, 0, stream>>>(qkv, Vt, mask, nrm);

  // out proj: ctx(nrm) @ wo -> ao
  gemm128_kernel<0><<<dim3(64, 8), 256, 0, stream>>>(nrm, 1024, woT, nullptr, nullptr, ao, nullptr, nullptr, 1024, 1024, 1.0f);

  // f = ao[:, :512] @ w1 + b1 ; sec = relu(ao[:, 512:] @ w2 + b2)
  gemm128_kernel<1><<<dim3(64, 16), 256, 0, stream>>>(ao,       1024, w1T, b1, nullptr, fbuf, nullptr, nullptr, 2048, 512, 1.0f);
  gemm128_kernel<2><<<dim3(64, 16), 256, 0, stream>>>(ao + 512, 1024, w2T, b2, nullptr, sec,  nullptr, nullptr, 2048, 512, 1.0f);

  convgate_kernel<<<8192, 256, 0, stream>>>(fbuf, cwT, cb, sec);

  // out = x + gated @ wp + bp
  gemm128_kernel<3><<<dim3(64, 8), 256, 0, stream>>>(sec, 2048, wpT, bp, x, nullptr, out, nullptr, 1024, 2048, 1.0f);
}

// Round 6
// 354.641 us; speedup vs baseline: 1.8252x; 1.0447x over previous
//
#include <hip/hip_runtime.h>

typedef unsigned short u16;
typedef __bf16 bf16x8 __attribute__((ext_vector_type(8)));
typedef short  s16x8  __attribute__((ext_vector_type(8)));
typedef float  f32x4  __attribute__((ext_vector_type(4)));

#define LDSPAD 72   // 64 + 8 bf16 pad (P^T tile)

// async global->LDS, 16B per lane, LDS dest = wave-uniform base + lane*16
#define GLOAD16(gp, lp) __builtin_amdgcn_global_load_lds( \
  (__attribute__((address_space(1))) unsigned int*)(unsigned long long)(const void*)(gp), \
  (__attribute__((address_space(3))) unsigned int*)(lp), 16, 0, 0)

static __device__ __forceinline__ u16 f2bf(float f){
  union { float f; unsigned int u; } v; v.f = f;
  unsigned int r = v.u + 0x7fffu + ((v.u >> 16) & 1u);
  return (u16)(r >> 16);
}
static __device__ __forceinline__ float bf2f(u16 u){
  union { unsigned int u; float f; } v; v.u = ((unsigned int)u) << 16; return v.f;
}
static __device__ __forceinline__ unsigned fbits(float f){
  union { float f; unsigned u; } v; v.f = f; return v.u;
}

// ---------------- weight transpose + fp32 -> bf16 (out = in^T) ----------------
__global__ __launch_bounds__(256) void wtrans_kernel(const float* __restrict__ in,
                                                     u16* __restrict__ out, int K, int N){
  __shared__ float tile[32][33];
  int n0 = blockIdx.x * 32, k0 = blockIdx.y * 32;
  int tx = threadIdx.x, ty = threadIdx.y;     // block (32, 8)
  #pragma unroll
  for (int i = 0; i < 4; ++i)
    tile[ty + i*8][tx] = in[(size_t)(k0 + ty + i*8) * N + n0 + tx];
  __syncthreads();
  #pragma unroll
  for (int i = 0; i < 4; ++i)
    out[(size_t)(n0 + ty + i*8) * K + k0 + tx] = f2bf(tile[tx][ty + i*8]);
}

// ---------------- conv weight transpose: cw (2048,1,4) -> cwT (4,2048) ----------------
__global__ __launch_bounds__(256) void cwtrans_kernel(const float* __restrict__ cw,
                                                      float* __restrict__ cwT){
  int i = blockIdx.x * 256 + threadIdx.x;   // 8192
  int c = i >> 2, j = i & 3;
  cwT[j * 2048 + c] = cw[i];
}

// ---------------- RMSNorm: fp32 in -> bf16 out ----------------
__global__ __launch_bounds__(256) void rmsnorm_kernel(const float* __restrict__ x,
                                                      const float* __restrict__ gamma,
                                                      u16* __restrict__ out){
  int row = blockIdx.x;                        // 8192 rows, D=1024
  const float* xr = x + (size_t)row * 1024;
  int tid = threadIdx.x;
  float4 xv = *(const float4*)(xr + tid * 4);
  float ss = xv.x*xv.x + xv.y*xv.y + xv.z*xv.z + xv.w*xv.w;
  #pragma unroll
  for (int off = 1; off < 64; off <<= 1) ss += __shfl_xor(ss, off);
  __shared__ float wsum[4];
  if ((tid & 63) == 0) wsum[tid >> 6] = ss;
  __syncthreads();
  float tot = wsum[0] + wsum[1] + wsum[2] + wsum[3];
  float r = rsqrtf(tot * (1.0f/1024.0f) + 1e-6f);
  const float4 gv = *(const float4*)(gamma + tid * 4);
  u16* o = out + (size_t)row * 1024 + tid * 4;
  o[0] = f2bf(xv.x * r * gv.x);
  o[1] = f2bf(xv.y * r * gv.y);
  o[2] = f2bf(xv.z * r * gv.z);
  o[3] = f2bf(xv.w * r * gv.w);
}

// ---------------- 128x128 double-buffered bf16 GEMM: C = A(MxK) * Bt(NxK)^T --------
// Prefetch-before-compute (T3-minimal), XOR-swizzled LDS (T2), XCD-chunked grid (T1).
// EPI: 0 ->bf16, 1 +bias->bf16, 2 +bias,relu->bf16, 3 +bias,+resid->fp32,
//      5 QKV fused: cols<1024 scaled ->outb, [1024,2048) ->outb,
//        n0>=2048 blocks -> vt[(col-2048)*8192 + row] via LDS transpose (coalesced)
template<int EPI>
__global__ __launch_bounds__(256) void gemm128_kernel(
    const u16* __restrict__ A, int lda,
    const u16* __restrict__ Bt,
    const float* __restrict__ bias,
    const float* __restrict__ resid,
    u16* __restrict__ outb, float* __restrict__ outf,
    u16* __restrict__ vt,
    int N, int K, float scale, int nm)
{
  __shared__ __align__(16) u16 As[2][128*64];
  __shared__ __align__(16) u16 Bs[2][128*64];
  int tid = threadIdx.x;
  int wid = tid >> 6, lane = tid & 63;
  int fr = lane & 15, fq = lane >> 4;
  int wr = wid >> 1, wc = wid & 1;
  // XCD-chunked bijective swizzle (gridDim.x % 8 == 0), m-fastest within chunk
  int l = ((int)blockIdx.x & 7) * ((int)gridDim.x >> 3) + ((int)blockIdx.x >> 3);
  int m0 = (l % nm) * 128, n0 = (l / nm) * 128;
  int srow = lane >> 3;            // dest row within 8-row group
  int csw  = (lane & 7) ^ srow;    // pre-swizzled source 16B-chunk (rule #21)
  int c7   = fr & 7;               // read-side row XOR
  f32x4 acc[4][4] = {};

  const u16* Abase = A  + (size_t)m0 * lda;
  const u16* Bbase = Bt + (size_t)n0 * K;

  auto STAGE = [&](int bsel, int kt){
    int k0 = kt << 6;
    #pragma unroll
    for (int i = 0; i < 4; ++i){
      int r = i*32 + wid*8;
      GLOAD16(Abase + (size_t)(r + srow) * lda + k0 + csw*8, &As[bsel][r*64]);
      GLOAD16(Bbase + (size_t)(r + srow) * K   + k0 + csw*8, &Bs[bsel][r*64]);
    }
  };

  int nt = K >> 6;
  STAGE(0, 0);
  __syncthreads();
  for (int kt = 0; kt < nt; ++kt){
    int cur = kt & 1;
    if (kt + 1 < nt) STAGE(cur ^ 1, kt + 1);   // prefetch overlaps with compute below
    #pragma unroll
    for (int ks = 0; ks < 2; ++ks){
      bf16x8 av[4], bv[4];
      #pragma unroll
      for (int mi = 0; mi < 4; ++mi)
        av[mi] = *(const bf16x8*)&As[cur][(wr*64 + mi*16 + fr)*64 + (((ks*4 + fq) ^ c7) * 8)];
      #pragma unroll
      for (int ni = 0; ni < 4; ++ni)
        bv[ni] = *(const bf16x8*)&Bs[cur][(wc*64 + ni*16 + fr)*64 + (((ks*4 + fq) ^ c7) * 8)];
      #pragma unroll
      for (int mi = 0; mi < 4; ++mi)
        #pragma unroll
        for (int ni = 0; ni < 4; ++ni)
          acc[mi][ni] = __builtin_amdgcn_mfma_f32_16x16x32_bf16(av[mi], bv[ni], acc[mi][ni], 0, 0, 0);
    }
    __syncthreads();   // drains prefetch; protects buf[cur] from next-iter overwrite
  }

  if (EPI == 5 && n0 >= 2048){
    // V^T epilogue: C-tile -> LDS transpose -> coalesced 16B writes into vt
    u16* Ct = &As[0][0];                 // 64 x 136 u16 view (17.4 KB <= 32 KB)
    #pragma unroll
    for (int p = 0; p < 2; ++p){
      __syncthreads();
      if (wc == p){
        #pragma unroll
        for (int ni = 0; ni < 4; ++ni)
          #pragma unroll
          for (int mi = 0; mi < 4; ++mi){
            int cl = ni*16 + fr;
            int rl = wr*64 + mi*16 + fq*4;
            uint2 pk;
            pk.x = (unsigned)f2bf(acc[mi][ni][0]) | ((unsigned)f2bf(acc[mi][ni][1]) << 16);
            pk.y = (unsigned)f2bf(acc[mi][ni][2]) | ((unsigned)f2bf(acc[mi][ni][3]) << 16);
            *(uint2*)&Ct[cl*136 + rl] = pk;
          }
      }
      __syncthreads();
      #pragma unroll
      for (int ci = 0; ci < 4; ++ci){
        int qq = ci*256 + tid;           // 0..1023
        int c = qq >> 4, off = (qq & 15) * 8;
        uint4 v = *(const uint4*)&Ct[c*136 + off];
        *(uint4*)&vt[(size_t)(n0 - 2048 + p*64 + c) * 8192 + m0 + off] = v;
      }
    }
    return;
  }

  // D layout: row = fq*4 + j, col = fr
  #pragma unroll
  for (int ni = 0; ni < 4; ++ni){
    int col = n0 + wc*64 + ni*16 + fr;
    float bvv = (EPI >= 1 && EPI <= 3) ? bias[col] : 0.0f;
    float scl = (EPI == 5) ? ((col < 1024) ? scale : 1.0f) : scale;
    #pragma unroll
    for (int mi = 0; mi < 4; ++mi){
      #pragma unroll
      for (int j = 0; j < 4; ++j){
        int row = m0 + wr*64 + mi*16 + fq*4 + j;
        float vv = acc[mi][ni][j] * scl + bvv;
        if (EPI == 2) vv = fmaxf(vv, 0.0f);
        size_t idx = (size_t)row * N + col;
        if (EPI == 3) outf[idx] = vv + resid[idx];
        else          outb[idx] = f2bf(vv);
      }
    }
  }
}

// ---------------- fused flash attention (swapped-operand, in-lane softmax) ----------------
// qkv: (B*S, 3072) bf16, Q cols pre-scaled by 0.125*log2e. Vt: (1024, 8192) = V^T.
// ctx out: (B*S, 1024) bf16.
__global__ __launch_bounds__(256) void attn_kernel(
    const u16* __restrict__ qkv, const u16* __restrict__ Vt,
    const int* __restrict__ mask, u16* __restrict__ ctx)
{
  __shared__ __align__(16) u16 Ks[64*64];
  __shared__ __align__(16) u16 Vs[64*64];
  __shared__ __align__(16) u16 Ps[64][LDSPAD];
  int tid = threadIdx.x;
  int wid = tid >> 6, lane = tid & 63;
  int fr = lane & 15, fq = lane >> 4;
  int q0 = blockIdx.x * 64;
  int bh = blockIdx.y;
  int b = bh >> 4, h = bh & 15;

  const u16* qb  = qkv + (size_t)b * 1024 * 3072 + h * 64;          // + s*3072 + d
  const u16* kb  = qb + 1024;
  const u16* vtb = Vt + (size_t)(h * 64) * 8192 + b * 1024;         // + d*8192 + s

  int lrow = lane >> 3;                   // 0..7
  int cs   = (lane & 7) ^ lrow;           // pre-swizzled source 16B-chunk
  int wbase = wid * 16;

  bf16x8 qf[2];
  {
    const u16* qp = qb + (size_t)(q0 + wid*16 + fr) * 3072 + fq * 8;
    qf[0] = *(const bf16x8*)(qp);
    qf[1] = *(const bf16x8*)(qp + 32);
  }
  f32x4 acc[4];   // O^T: acc[nt][j] = O[d = nt*16+fq*4+j][q = wid*16+fr]
  #pragma unroll
  for (int i = 0; i < 4; ++i) acc[i] = (f32x4){0.f, 0.f, 0.f, 0.f};
  float m = -1e30f, lsum = 0.f;
  int c7 = fr & 7;   // read-side row XOR

  for (int t = 0; t < 16; ++t){
    int kv0 = t * 64;
    __syncthreads();
    #pragma unroll
    for (int i = 0; i < 2; ++i){
      int r = wbase + i*8 + lrow;
      GLOAD16(kb  + (size_t)(kv0 + r) * 3072 + cs * 8, &Ks[(wbase + i*8) * 64]);
      GLOAD16(vtb + (size_t)r * 8192 + kv0 + cs * 8,   &Vs[(wbase + i*8) * 64]);
    }
    __syncthreads();

    // QK^T (swapped): sc[nt][j] = S^T[k = nt*16+fq*4+j][q = wid*16+fr]
    f32x4 sc[4];
    #pragma unroll
    for (int nt = 0; nt < 4; ++nt) sc[nt] = (f32x4){0.f, 0.f, 0.f, 0.f};
    __builtin_amdgcn_s_setprio(1);
    #pragma unroll
    for (int ks = 0; ks < 2; ++ks){
      #pragma unroll
      for (int nt = 0; nt < 4; ++nt){
        bf16x8 kv = *(const bf16x8*)&Ks[(nt*16 + fr)*64 + (((ks*4 + fq) ^ c7) * 8)];
        sc[nt] = __builtin_amdgcn_mfma_f32_16x16x32_bf16(kv, qf[ks], sc[nt], 0, 0, 0);
      }
    }
    __builtin_amdgcn_s_setprio(0);

    // mask (k rows per lane: kv0 + nt*16 + fq*4 + j)
    #pragma unroll
    for (int nt = 0; nt < 4; ++nt){
      int4 mv = *(const int4*)&mask[b * 1024 + kv0 + nt*16 + fq*4];
      int mvals[4] = {mv.x, mv.y, mv.z, mv.w};
      #pragma unroll
      for (int j = 0; j < 4; ++j)
        sc[nt][j] = mvals[j] ? sc[nt][j] : -1e9f;
    }

    // in-lane softmax (log2 domain)
    float pmax = -1e30f;
    #pragma unroll
    for (int nt = 0; nt < 4; ++nt)
      #pragma unroll
      for (int j = 0; j < 4; ++j)
        pmax = fmaxf(pmax, sc[nt][j]);
    pmax = fmaxf(pmax, __shfl_xor(pmax, 16));
    pmax = fmaxf(pmax, __shfl_xor(pmax, 32));
    if (!__all(pmax <= m + 8.0f)){            // defer-max (T13)
      float mnew = fmaxf(m, pmax);
      float corr = exp2f(m - mnew);
      #pragma unroll
      for (int nt = 0; nt < 4; ++nt)
        #pragma unroll
        for (int j = 0; j < 4; ++j)
          acc[nt][j] *= corr;
      lsum *= corr;
      m = mnew;
    }
    float p[4][4];
    float ls = 0.f;
    #pragma unroll
    for (int nt = 0; nt < 4; ++nt)
      #pragma unroll
      for (int j = 0; j < 4; ++j){
        float pv = exp2f(sc[nt][j] - m);
        p[nt][j] = pv;
        ls += pv;
      }
    lsum += ls;

    // P^T -> per-wave LDS rows (truncate-to-bf16 pairs via v_perm), no barrier needed
    #pragma unroll
    for (int nt = 0; nt < 4; ++nt){
      unsigned d0 = __builtin_amdgcn_perm(fbits(p[nt][1]), fbits(p[nt][0]), 0x07060302u);
      unsigned d1 = __builtin_amdgcn_perm(fbits(p[nt][3]), fbits(p[nt][2]), 0x07060302u);
      *(unsigned*)&Ps[wid*16 + fr][nt*16 + fq*4]     = d0;
      *(unsigned*)&Ps[wid*16 + fr][nt*16 + fq*4 + 2] = d1;
    }

    // PV (swapped): acc[nt] += mfma(V^T frag, P^T frag)
    __builtin_amdgcn_s_setprio(1);
    #pragma unroll
    for (int ks = 0; ks < 2; ++ks){
      bf16x8 pb = *(const bf16x8*)&Ps[wid*16 + fr][ks*32 + fq*8];
      #pragma unroll
      for (int nt = 0; nt < 4; ++nt){
        bf16x8 vv = *(const bf16x8*)&Vs[(nt*16 + fr)*64 + (((ks*4 + fq) ^ c7) * 8)];
        acc[nt] = __builtin_amdgcn_mfma_f32_16x16x32_bf16(vv, pb, acc[nt], 0, 0, 0);
      }
    }
    __builtin_amdgcn_s_setprio(0);
  }

  lsum += __shfl_xor(lsum, 16);
  lsum += __shfl_xor(lsum, 32);
  float invl = 1.0f / lsum;

  // O^T write-back: d = nt*16+fq*4+j, q = wid*16+fr
  size_t rowbase = ((size_t)b * 1024 + q0 + wid*16 + fr) * 1024 + h * 64;
  #pragma unroll
  for (int nt = 0; nt < 4; ++nt){
    unsigned lo = (unsigned)f2bf(acc[nt][0] * invl) | ((unsigned)f2bf(acc[nt][1] * invl) << 16);
    unsigned hi = (unsigned)f2bf(acc[nt][2] * invl) | ((unsigned)f2bf(acc[nt][3] * invl) << 16);
    uint2 pk; pk.x = lo; pk.y = hi;
    *(uint2*)&ctx[rowbase + nt*16 + fq*4] = pk;
  }
}

// ---------------- depthwise dilated conv (K=4, dil=2, pad 3) + gate, in-place over sec ----------------
// cwT: (4, 2048) f32 transposed conv weights -> coalesced vector loads
__global__ __launch_bounds__(256) void convgate_kernel(
    const u16* __restrict__ f, const float* __restrict__ cwT,
    const float* __restrict__ cb, u16* __restrict__ sec_inout)
{
  size_t gid = (size_t)blockIdx.x * blockDim.x + threadIdx.x;  // 2M threads, 8 ch each
  int c0 = (int)(gid & 255) * 8;
  int t  = (int)((gid >> 8) & 1023);
  int b  = (int)(gid >> 18);
  const u16* fb = f + ((size_t)b * 1024) * 2048;

  // coalesced weight/bias loads (lane stride 32B)
  float4 w[4][2];
  #pragma unroll
  for (int j = 0; j < 4; ++j){
    w[j][0] = *(const float4*)&cwT[j*2048 + c0];
    w[j][1] = *(const float4*)&cwT[j*2048 + c0 + 4];
  }
  float4 cb0 = *(const float4*)&cb[c0];
  float4 cb1 = *(const float4*)&cb[c0 + 4];
  float acc[8] = {cb0.x, cb0.y, cb0.z, cb0.w, cb1.x, cb1.y, cb1.z, cb1.w};

  #pragma unroll
  for (int j = 0; j < 4; ++j){
    int tt = t - 3 + 2 * j;
    if (tt >= 0 && tt < 1024){     // block-uniform branch (t is block-uniform)
      s16x8 fv = *(const s16x8*)(fb + (size_t)tt * 2048 + c0);
      const float* wj = (const float*)&w[j][0];
      #pragma unroll
      for (int e = 0; e < 8; ++e) acc[e] += bf2f((u16)fv[e]) * wj[e];
    }
  }
  u16* sp = sec_inout + (((size_t)b * 1024 + t) * 2048 + c0);
  s16x8 sv = *(const s16x8*)sp;
  s16x8 ov;
  #pragma unroll
  for (int e = 0; e < 8; ++e) ov[e] = (short)f2bf(acc[e] * bf2f((u16)sv[e]));
  *(s16x8*)sp = ov;
}

// ---------------- host launch ----------------
extern "C" void kernel_launch(void* const* d_in, const int* in_sizes, int n_in,
                              void* d_out, int out_size, void* d_ws, size_t ws_size,
                              hipStream_t stream)
{
  const float* x     = (const float*)d_in[0];
  const int*   mask  = (const int*)  d_in[1];
  const float* gamma = (const float*)d_in[2];
  const float* wq    = (const float*)d_in[3];
  const float* wk    = (const float*)d_in[4];
  const float* wv    = (const float*)d_in[5];
  const float* wo    = (const float*)d_in[6];
  const float* w1    = (const float*)d_in[7];
  const float* b1    = (const float*)d_in[8];
  const float* cw    = (const float*)d_in[9];
  const float* cb    = (const float*)d_in[10];
  const float* w2    = (const float*)d_in[11];
  const float* b2    = (const float*)d_in[12];
  const float* wp    = (const float*)d_in[13];
  const float* bp    = (const float*)d_in[14];
  float* out = (float*)d_out;

  char* p = (char*)d_ws;
  auto alloc = [&](size_t bytes){ char* r = p; p += (bytes + 255) & ~(size_t)255; return r; };
  u16*   wqkvT = (u16*)alloc((size_t)3072*1024*2);  // wq^T | wk^T | wv^T contiguous
  u16*   woT   = (u16*)alloc((size_t)1024*1024*2);
  u16*   w1T   = (u16*)alloc((size_t)2048*512*2);
  u16*   w2T   = (u16*)alloc((size_t)2048*512*2);
  u16*   wpT   = (u16*)alloc((size_t)1024*2048*2);
  float* cwT   = (float*)alloc((size_t)4*2048*4);
  u16*   nrm   = (u16*)alloc((size_t)8192*1024*2);   // later: attn ctx
  u16*   qkv   = (u16*)alloc((size_t)8192*3072*2);   // later: [0:16MB] ao, [16:48MB] f
  u16*   sec   = (u16*)alloc((size_t)8192*2048*2);   // first 16MB doubles as Vt before w2 GEMM
  u16* Vt   = sec;
  u16* ao   = qkv;
  u16* fbuf = qkv + (size_t)8192*1024;
  (void)ws_size; (void)in_sizes; (void)n_in; (void)out_size;

  const float QSCALE = 0.125f * 1.44269504088896340736f;  // 1/sqrt(64) * log2(e)

  dim3 tb32(32, 8);
  wtrans_kernel<<<dim3(32, 32), tb32, 0, stream>>>(wq, wqkvT,                     1024, 1024);
  wtrans_kernel<<<dim3(32, 32), tb32, 0, stream>>>(wk, wqkvT + (size_t)1024*1024, 1024, 1024);
  wtrans_kernel<<<dim3(32, 32), tb32, 0, stream>>>(wv, wqkvT + (size_t)2048*1024, 1024, 1024);
  wtrans_kernel<<<dim3(32, 32), tb32, 0, stream>>>(wo, woT, 1024, 1024);
  wtrans_kernel<<<dim3(64, 16), tb32, 0, stream>>>(w1, w1T, 512, 2048);
  wtrans_kernel<<<dim3(64, 16), tb32, 0, stream>>>(w2, w2T, 512, 2048);
  wtrans_kernel<<<dim3(32, 64), tb32, 0, stream>>>(wp, wpT, 2048, 1024);
  cwtrans_kernel<<<32, 256, 0, stream>>>(cw, cwT);

  rmsnorm_kernel<<<8192, 256, 0, stream>>>(x, gamma, nrm);

  // fused QKV: (8192x1024) @ (1024x3072) -> qkv (q,k) + Vt (V^T direct)
  gemm128_kernel<5><<<1536, 256, 0, stream>>>(nrm, 1024, wqkvT, nullptr, nullptr, qkv, nullptr, Vt, 3072, 1024, QSCALE, 64);

  attn_kernel<<<dim3(16, 128), 256, 0, stream>>>(qkv, Vt, mask, nrm);

  // out proj: ctx(nrm) @ wo -> ao
  gemm128_kernel<0><<<512, 256, 0, stream>>>(nrm, 1024, woT, nullptr, nullptr, ao, nullptr, nullptr, 1024, 1024, 1.0f, 64);

  // f = ao[:, :512] @ w1 + b1 ; sec = relu(ao[:, 512:] @ w2 + b2)
  gemm128_kernel<1><<<1024, 256, 0, stream>>>(ao,       1024, w1T, b1, nullptr, fbuf, nullptr, nullptr, 2048, 512, 1.0f, 64);
  gemm128_kernel<2><<<1024, 256, 0, stream>>>(ao + 512, 1024, w2T, b2, nullptr, sec,  nullptr, nullptr, 2048, 512, 1.0f, 64);

  convgate_kernel<<<8192, 256, 0, stream>>>(fbuf, cwT, cb, sec);

  // out = x + gated @ wp + bp
  gemm128_kernel<3><<<512, 256, 0, stream>>>(sec, 2048, wpT, bp, x, nullptr, out, nullptr, 1024, 2048, 1.0f, 64);
}

// Round 7
// 334.342 us; speedup vs baseline: 1.9360x; 1.0607x over previous
//
#include <hip/hip_runtime.h>

typedef unsigned short u16;
typedef __bf16 bf16x8 __attribute__((ext_vector_type(8)));
typedef short  s16x8  __attribute__((ext_vector_type(8)));
typedef float  f32x4  __attribute__((ext_vector_type(4)));

#define LDSPAD 72   // 64 + 8 bf16 pad (P^T tile)

// async global->LDS, 16B per lane, LDS dest = wave-uniform base + lane*16
#define GLOAD16(gp, lp) __builtin_amdgcn_global_load_lds( \
  (__attribute__((address_space(1))) unsigned int*)(unsigned long long)(const void*)(gp), \
  (__attribute__((address_space(3))) unsigned int*)(lp), 16, 0, 0)

static __device__ __forceinline__ u16 f2bf(float f){
  union { float f; unsigned int u; } v; v.f = f;
  unsigned int r = v.u + 0x7fffu + ((v.u >> 16) & 1u);
  return (u16)(r >> 16);
}
static __device__ __forceinline__ float bf2f(u16 u){
  union { unsigned int u; float f; } v; v.u = ((unsigned int)u) << 16; return v.f;
}
static __device__ __forceinline__ unsigned fbits(float f){
  union { float f; unsigned u; } v; v.f = f; return v.u;
}

// ---------------- weight transpose + fp32 -> bf16 (out = in^T) ----------------
__global__ __launch_bounds__(256) void wtrans_kernel(const float* __restrict__ in,
                                                     u16* __restrict__ out, int K, int N){
  __shared__ float tile[32][33];
  int n0 = blockIdx.x * 32, k0 = blockIdx.y * 32;
  int tx = threadIdx.x, ty = threadIdx.y;     // block (32, 8)
  #pragma unroll
  for (int i = 0; i < 4; ++i)
    tile[ty + i*8][tx] = in[(size_t)(k0 + ty + i*8) * N + n0 + tx];
  __syncthreads();
  #pragma unroll
  for (int i = 0; i < 4; ++i)
    out[(size_t)(n0 + ty + i*8) * K + k0 + tx] = f2bf(tile[tx][ty + i*8]);
}

// ---------------- conv weight transpose: cw (2048,1,4) -> cwT (4,2048) ----------------
__global__ __launch_bounds__(256) void cwtrans_kernel(const float* __restrict__ cw,
                                                      float* __restrict__ cwT){
  int i = blockIdx.x * 256 + threadIdx.x;   // 8192
  int c = i >> 2, j = i & 3;
  cwT[j * 2048 + c] = cw[i];
}

// ---------------- RMSNorm: fp32 in -> bf16 out ----------------
__global__ __launch_bounds__(256) void rmsnorm_kernel(const float* __restrict__ x,
                                                      const float* __restrict__ gamma,
                                                      u16* __restrict__ out){
  int row = blockIdx.x;                        // 8192 rows, D=1024
  const float* xr = x + (size_t)row * 1024;
  int tid = threadIdx.x;
  float4 xv = *(const float4*)(xr + tid * 4);
  float ss = xv.x*xv.x + xv.y*xv.y + xv.z*xv.z + xv.w*xv.w;
  #pragma unroll
  for (int off = 1; off < 64; off <<= 1) ss += __shfl_xor(ss, off);
  __shared__ float wsum[4];
  if ((tid & 63) == 0) wsum[tid >> 6] = ss;
  __syncthreads();
  float tot = wsum[0] + wsum[1] + wsum[2] + wsum[3];
  float r = rsqrtf(tot * (1.0f/1024.0f) + 1e-6f);
  const float4 gv = *(const float4*)(gamma + tid * 4);
  u16* o = out + (size_t)row * 1024 + tid * 4;
  o[0] = f2bf(xv.x * r * gv.x);
  o[1] = f2bf(xv.y * r * gv.y);
  o[2] = f2bf(xv.z * r * gv.z);
  o[3] = f2bf(xv.w * r * gv.w);
}

// ---------------- 128x128 double-buffered bf16 GEMM: C = A(MxK) * Bt(NxK)^T --------
// Prefetch-before-compute, XOR-swizzled LDS (T2). Linear dispatch (XCD swizzle reverted:
// round-6 counters showed it 4x'd FETCH_SIZE by breaking L3 sharing of A).
// EPI: 0 ->bf16, 1 +bias->bf16, 2 +bias,relu->bf16, 3 +bias,+resid->fp32,
//      5 QKV fused: cols<1024 scaled ->outb, [1024,2048) ->outb,
//        n0>=2048 blocks -> vt[(col-2048)*8192 + row] via LDS transpose (coalesced)
template<int EPI>
__global__ __launch_bounds__(256) void gemm128_kernel(
    const u16* __restrict__ A, int lda,
    const u16* __restrict__ Bt,
    const float* __restrict__ bias,
    const float* __restrict__ resid,
    u16* __restrict__ outb, float* __restrict__ outf,
    u16* __restrict__ vt,
    int N, int K, float scale, int nm)
{
  __shared__ __align__(16) u16 As[2][128*64];
  __shared__ __align__(16) u16 Bs[2][128*64];
  int tid = threadIdx.x;
  int wid = tid >> 6, lane = tid & 63;
  int fr = lane & 15, fq = lane >> 4;
  int wr = wid >> 1, wc = wid & 1;
  int l = (int)blockIdx.x;               // linear, m-fastest (L3-friendly round-robin)
  int m0 = (l % nm) * 128, n0 = (l / nm) * 128;
  int srow = lane >> 3;            // dest row within 8-row group
  int csw  = (lane & 7) ^ srow;    // pre-swizzled source 16B-chunk (rule #21)
  int c7   = fr & 7;               // read-side row XOR
  f32x4 acc[4][4] = {};

  const u16* Abase = A  + (size_t)m0 * lda;
  const u16* Bbase = Bt + (size_t)n0 * K;

  auto STAGE = [&](int bsel, int kt){
    int k0 = kt << 6;
    #pragma unroll
    for (int i = 0; i < 4; ++i){
      int r = i*32 + wid*8;
      GLOAD16(Abase + (size_t)(r + srow) * lda + k0 + csw*8, &As[bsel][r*64]);
      GLOAD16(Bbase + (size_t)(r + srow) * K   + k0 + csw*8, &Bs[bsel][r*64]);
    }
  };

  int nt = K >> 6;
  STAGE(0, 0);
  __syncthreads();
  for (int kt = 0; kt < nt; ++kt){
    int cur = kt & 1;
    if (kt + 1 < nt) STAGE(cur ^ 1, kt + 1);   // prefetch overlaps with compute below
    #pragma unroll
    for (int ks = 0; ks < 2; ++ks){
      bf16x8 av[4], bv[4];
      #pragma unroll
      for (int mi = 0; mi < 4; ++mi)
        av[mi] = *(const bf16x8*)&As[cur][(wr*64 + mi*16 + fr)*64 + (((ks*4 + fq) ^ c7) * 8)];
      #pragma unroll
      for (int ni = 0; ni < 4; ++ni)
        bv[ni] = *(const bf16x8*)&Bs[cur][(wc*64 + ni*16 + fr)*64 + (((ks*4 + fq) ^ c7) * 8)];
      #pragma unroll
      for (int mi = 0; mi < 4; ++mi)
        #pragma unroll
        for (int ni = 0; ni < 4; ++ni)
          acc[mi][ni] = __builtin_amdgcn_mfma_f32_16x16x32_bf16(av[mi], bv[ni], acc[mi][ni], 0, 0, 0);
    }
    __syncthreads();   // drains prefetch; protects buf[cur] from next-iter overwrite
  }

  if (EPI == 5 && n0 >= 2048){
    // V^T epilogue: C-tile -> LDS transpose -> coalesced 16B writes into vt
    u16* Ct = &As[0][0];                 // 64 x 136 u16 view
    #pragma unroll
    for (int p = 0; p < 2; ++p){
      __syncthreads();
      if (wc == p){
        #pragma unroll
        for (int ni = 0; ni < 4; ++ni)
          #pragma unroll
          for (int mi = 0; mi < 4; ++mi){
            int cl = ni*16 + fr;
            int rl = wr*64 + mi*16 + fq*4;
            uint2 pk;
            pk.x = (unsigned)f2bf(acc[mi][ni][0]) | ((unsigned)f2bf(acc[mi][ni][1]) << 16);
            pk.y = (unsigned)f2bf(acc[mi][ni][2]) | ((unsigned)f2bf(acc[mi][ni][3]) << 16);
            *(uint2*)&Ct[cl*136 + rl] = pk;
          }
      }
      __syncthreads();
      #pragma unroll
      for (int ci = 0; ci < 4; ++ci){
        int qq = ci*256 + tid;           // 0..1023
        int c = qq >> 4, off = (qq & 15) * 8;
        uint4 v = *(const uint4*)&Ct[c*136 + off];
        *(uint4*)&vt[(size_t)(n0 - 2048 + p*64 + c) * 8192 + m0 + off] = v;
      }
    }
    return;
  }

  // D layout: row = fq*4 + j, col = fr
  #pragma unroll
  for (int ni = 0; ni < 4; ++ni){
    int col = n0 + wc*64 + ni*16 + fr;
    float bvv = (EPI >= 1 && EPI <= 3) ? bias[col] : 0.0f;
    float scl = (EPI == 5) ? ((col < 1024) ? scale : 1.0f) : scale;
    #pragma unroll
    for (int mi = 0; mi < 4; ++mi){
      #pragma unroll
      for (int j = 0; j < 4; ++j){
        int row = m0 + wr*64 + mi*16 + fq*4 + j;
        float vv = acc[mi][ni][j] * scl + bvv;
        if (EPI == 2) vv = fmaxf(vv, 0.0f);
        size_t idx = (size_t)row * N + col;
        if (EPI == 3) outf[idx] = vv + resid[idx];
        else          outb[idx] = f2bf(vv);
      }
    }
  }
}

// ---------------- fused flash attention (swapped-operand, reg-fragment, stage-overlap) ----
// qkv: (B*S, 3072) bf16, Q cols pre-scaled by 0.125*log2e. Vt: (1024, 8192) = V^T.
// ctx out: (B*S, 1024) bf16.  2 Q-subtiles (128 q-rows) per block.
// Per tile: barrier -> kf/vf LDS->reg (b128) -> barrier -> STAGE(t+1) overlaps
// QK/softmax/PV which run entirely from regs (+per-wave Ps region, no barrier).
__global__ __launch_bounds__(256) void attn_kernel(
    const u16* __restrict__ qkv, const u16* __restrict__ Vt,
    const int* __restrict__ mask, u16* __restrict__ ctx)
{
  __shared__ __align__(16) u16 Ks[64*64];
  __shared__ __align__(16) u16 Vs[64*64];
  __shared__ __align__(16) u16 Ps[64][LDSPAD];
  int tid = threadIdx.x;
  int wid = tid >> 6, lane = tid & 63;
  int fr = lane & 15, fq = lane >> 4;
  int q0 = blockIdx.x * 128;
  int bh = blockIdx.y;
  int b = bh >> 4, h = bh & 15;

  const u16* qb  = qkv + (size_t)b * 1024 * 3072 + h * 64;          // + s*3072 + d
  const u16* kb  = qb + 1024;
  const u16* vtb = Vt + (size_t)(h * 64) * 8192 + b * 1024;         // + d*8192 + s

  int lrow = lane >> 3;                   // 0..7
  int cs   = (lane & 7) ^ lrow;           // pre-swizzled source 16B-chunk
  int wbase = wid * 16;
  int c7 = fr & 7;                        // read-side row XOR

  bf16x8 qf[2][2];
  #pragma unroll
  for (int s = 0; s < 2; ++s){
    const u16* qp = qb + (size_t)(q0 + s*64 + wid*16 + fr) * 3072 + fq * 8;
    qf[s][0] = *(const bf16x8*)(qp);
    qf[s][1] = *(const bf16x8*)(qp + 32);
  }
  f32x4 acc[2][4];
  #pragma unroll
  for (int s = 0; s < 2; ++s)
    #pragma unroll
    for (int i = 0; i < 4; ++i) acc[s][i] = (f32x4){0.f, 0.f, 0.f, 0.f};
  float mrun[2] = {-1e30f, -1e30f}, lsum[2] = {0.f, 0.f};

  auto STAGE = [&](int t){
    int kv0 = t * 64;
    #pragma unroll
    for (int i = 0; i < 2; ++i){
      int r = wbase + i*8 + lrow;
      GLOAD16(kb  + (size_t)(kv0 + r) * 3072 + cs * 8, &Ks[(wbase + i*8) * 64]);
      GLOAD16(vtb + (size_t)r * 8192 + kv0 + cs * 8,   &Vs[(wbase + i*8) * 64]);
    }
  };

  STAGE(0);
  for (int t = 0; t < 16; ++t){
    int kv0 = t * 64;
    __syncthreads();                 // staged tile t visible (each wave drained own vmcnt)
    // K,V fragments -> registers
    bf16x8 kf[2][4], vf[2][4];
    #pragma unroll
    for (int ks = 0; ks < 2; ++ks)
      #pragma unroll
      for (int nt = 0; nt < 4; ++nt){
        kf[ks][nt] = *(const bf16x8*)&Ks[(nt*16 + fr)*64 + (((ks*4 + fq) ^ c7) * 8)];
        vf[ks][nt] = *(const bf16x8*)&Vs[(nt*16 + fr)*64 + (((ks*4 + fq) ^ c7) * 8)];
      }
    __syncthreads();                 // all waves done reading LDS K/V (lgkmcnt(0) implied)
    if (t + 1 < 16) STAGE(t + 1);    // overwrite overlaps all compute below

    #pragma unroll
    for (int s = 0; s < 2; ++s){
      // QK^T (swapped): sc[nt][j] = S^T[k = nt*16+fq*4+j][q = s*64+wid*16+fr]
      f32x4 sc[4];
      #pragma unroll
      for (int nt = 0; nt < 4; ++nt) sc[nt] = (f32x4){0.f, 0.f, 0.f, 0.f};
      __builtin_amdgcn_s_setprio(1);
      #pragma unroll
      for (int ks = 0; ks < 2; ++ks)
        #pragma unroll
        for (int nt = 0; nt < 4; ++nt)
          sc[nt] = __builtin_amdgcn_mfma_f32_16x16x32_bf16(kf[ks][nt], qf[s][ks], sc[nt], 0, 0, 0);
      __builtin_amdgcn_s_setprio(0);

      // mask (k rows per lane: kv0 + nt*16 + fq*4 + j)
      #pragma unroll
      for (int nt = 0; nt < 4; ++nt){
        int4 mv = *(const int4*)&mask[b * 1024 + kv0 + nt*16 + fq*4];
        int mvals[4] = {mv.x, mv.y, mv.z, mv.w};
        #pragma unroll
        for (int j = 0; j < 4; ++j)
          sc[nt][j] = mvals[j] ? sc[nt][j] : -1e9f;
      }

      // in-lane softmax (log2 domain)
      float pmax = -1e30f;
      #pragma unroll
      for (int nt = 0; nt < 4; ++nt)
        #pragma unroll
        for (int j = 0; j < 4; ++j)
          pmax = fmaxf(pmax, sc[nt][j]);
      pmax = fmaxf(pmax, __shfl_xor(pmax, 16));
      pmax = fmaxf(pmax, __shfl_xor(pmax, 32));
      if (!__all(pmax <= mrun[s] + 8.0f)){      // defer-max (T13)
        float mnew = fmaxf(mrun[s], pmax);
        float corr = exp2f(mrun[s] - mnew);
        #pragma unroll
        for (int nt = 0; nt < 4; ++nt)
          #pragma unroll
          for (int j = 0; j < 4; ++j)
            acc[s][nt][j] *= corr;
        lsum[s] *= corr;
        mrun[s] = mnew;
      }
      float p[4][4];
      float ls = 0.f;
      #pragma unroll
      for (int nt = 0; nt < 4; ++nt)
        #pragma unroll
        for (int j = 0; j < 4; ++j){
          float pv = exp2f(sc[nt][j] - mrun[s]);
          p[nt][j] = pv;
          ls += pv;
        }
      lsum[s] += ls;

      // P^T -> per-wave LDS rows (truncate-to-bf16 pairs via v_perm), same-wave ordering
      #pragma unroll
      for (int nt = 0; nt < 4; ++nt){
        unsigned d0 = __builtin_amdgcn_perm(fbits(p[nt][1]), fbits(p[nt][0]), 0x07060302u);
        unsigned d1 = __builtin_amdgcn_perm(fbits(p[nt][3]), fbits(p[nt][2]), 0x07060302u);
        *(unsigned*)&Ps[wid*16 + fr][nt*16 + fq*4]     = d0;
        *(unsigned*)&Ps[wid*16 + fr][nt*16 + fq*4 + 2] = d1;
      }

      // PV (swapped): acc[s][nt] += mfma(V^T frag (regs), P^T frag)
      __builtin_amdgcn_s_setprio(1);
      #pragma unroll
      for (int ks = 0; ks < 2; ++ks){
        bf16x8 pb = *(const bf16x8*)&Ps[wid*16 + fr][ks*32 + fq*8];
        #pragma unroll
        for (int nt = 0; nt < 4; ++nt)
          acc[s][nt] = __builtin_amdgcn_mfma_f32_16x16x32_bf16(vf[ks][nt], pb, acc[s][nt], 0, 0, 0);
      }
      __builtin_amdgcn_s_setprio(0);
    }
  }

  #pragma unroll
  for (int s = 0; s < 2; ++s){
    float ltot = lsum[s];
    ltot += __shfl_xor(ltot, 16);
    ltot += __shfl_xor(ltot, 32);
    float invl = 1.0f / ltot;
    size_t rowbase = ((size_t)b * 1024 + q0 + s*64 + wid*16 + fr) * 1024 + h * 64;
    #pragma unroll
    for (int nt = 0; nt < 4; ++nt){
      unsigned lo = (unsigned)f2bf(acc[s][nt][0] * invl) | ((unsigned)f2bf(acc[s][nt][1] * invl) << 16);
      unsigned hi = (unsigned)f2bf(acc[s][nt][2] * invl) | ((unsigned)f2bf(acc[s][nt][3] * invl) << 16);
      uint2 pk; pk.x = lo; pk.y = hi;
      *(uint2*)&ctx[rowbase + nt*16 + fq*4] = pk;
    }
  }
}

// ---------------- depthwise dilated conv (K=4, dil=2, pad 3) + gate, in-place over sec ----------------
// cwT: (4, 2048) f32 transposed conv weights -> coalesced vector loads
__global__ __launch_bounds__(256) void convgate_kernel(
    const u16* __restrict__ f, const float* __restrict__ cwT,
    const float* __restrict__ cb, u16* __restrict__ sec_inout)
{
  size_t gid = (size_t)blockIdx.x * blockDim.x + threadIdx.x;  // 2M threads, 8 ch each
  int c0 = (int)(gid & 255) * 8;
  int t  = (int)((gid >> 8) & 1023);
  int b  = (int)(gid >> 18);
  const u16* fb = f + ((size_t)b * 1024) * 2048;

  // coalesced weight/bias loads (lane stride 32B)
  float4 w[4][2];
  #pragma unroll
  for (int j = 0; j < 4; ++j){
    w[j][0] = *(const float4*)&cwT[j*2048 + c0];
    w[j][1] = *(const float4*)&cwT[j*2048 + c0 + 4];
  }
  float4 cb0 = *(const float4*)&cb[c0];
  float4 cb1 = *(const float4*)&cb[c0 + 4];
  float acc[8] = {cb0.x, cb0.y, cb0.z, cb0.w, cb1.x, cb1.y, cb1.z, cb1.w};

  #pragma unroll
  for (int j = 0; j < 4; ++j){
    int tt = t - 3 + 2 * j;
    if (tt >= 0 && tt < 1024){     // block-uniform branch (t is block-uniform)
      s16x8 fv = *(const s16x8*)(fb + (size_t)tt * 2048 + c0);
      const float* wj = (const float*)&w[j][0];
      #pragma unroll
      for (int e = 0; e < 8; ++e) acc[e] += bf2f((u16)fv[e]) * wj[e];
    }
  }
  u16* sp = sec_inout + (((size_t)b * 1024 + t) * 2048 + c0);
  s16x8 sv = *(const s16x8*)sp;
  s16x8 ov;
  #pragma unroll
  for (int e = 0; e < 8; ++e) ov[e] = (short)f2bf(acc[e] * bf2f((u16)sv[e]));
  *(s16x8*)sp = ov;
}

// ---------------- host launch ----------------
extern "C" void kernel_launch(void* const* d_in, const int* in_sizes, int n_in,
                              void* d_out, int out_size, void* d_ws, size_t ws_size,
                              hipStream_t stream)
{
  const float* x     = (const float*)d_in[0];
  const int*   mask  = (const int*)  d_in[1];
  const float* gamma = (const float*)d_in[2];
  const float* wq    = (const float*)d_in[3];
  const float* wk    = (const float*)d_in[4];
  const float* wv    = (const float*)d_in[5];
  const float* wo    = (const float*)d_in[6];
  const float* w1    = (const float*)d_in[7];
  const float* b1    = (const float*)d_in[8];
  const float* cw    = (const float*)d_in[9];
  const float* cb    = (const float*)d_in[10];
  const float* w2    = (const float*)d_in[11];
  const float* b2    = (const float*)d_in[12];
  const float* wp    = (const float*)d_in[13];
  const float* bp    = (const float*)d_in[14];
  float* out = (float*)d_out;

  char* p = (char*)d_ws;
  auto alloc = [&](size_t bytes){ char* r = p; p += (bytes + 255) & ~(size_t)255; return r; };
  u16*   wqkvT = (u16*)alloc((size_t)3072*1024*2);  // wq^T | wk^T | wv^T contiguous
  u16*   woT   = (u16*)alloc((size_t)1024*1024*2);
  u16*   w1T   = (u16*)alloc((size_t)2048*512*2);
  u16*   w2T   = (u16*)alloc((size_t)2048*512*2);
  u16*   wpT   = (u16*)alloc((size_t)1024*2048*2);
  float* cwT   = (float*)alloc((size_t)4*2048*4);
  u16*   nrm   = (u16*)alloc((size_t)8192*1024*2);   // later: attn ctx
  u16*   qkv   = (u16*)alloc((size_t)8192*3072*2);   // later: [0:16MB] ao, [16:48MB] f
  u16*   sec   = (u16*)alloc((size_t)8192*2048*2);   // first 16MB doubles as Vt before w2 GEMM
  u16* Vt   = sec;
  u16* ao   = qkv;
  u16* fbuf = qkv + (size_t)8192*1024;
  (void)ws_size; (void)in_sizes; (void)n_in; (void)out_size;

  const float QSCALE = 0.125f * 1.44269504088896340736f;  // 1/sqrt(64) * log2(e)

  dim3 tb32(32, 8);
  wtrans_kernel<<<dim3(32, 32), tb32, 0, stream>>>(wq, wqkvT,                     1024, 1024);
  wtrans_kernel<<<dim3(32, 32), tb32, 0, stream>>>(wk, wqkvT + (size_t)1024*1024, 1024, 1024);
  wtrans_kernel<<<dim3(32, 32), tb32, 0, stream>>>(wv, wqkvT + (size_t)2048*1024, 1024, 1024);
  wtrans_kernel<<<dim3(32, 32), tb32, 0, stream>>>(wo, woT, 1024, 1024);
  wtrans_kernel<<<dim3(64, 16), tb32, 0, stream>>>(w1, w1T, 512, 2048);
  wtrans_kernel<<<dim3(64, 16), tb32, 0, stream>>>(w2, w2T, 512, 2048);
  wtrans_kernel<<<dim3(32, 64), tb32, 0, stream>>>(wp, wpT, 2048, 1024);
  cwtrans_kernel<<<32, 256, 0, stream>>>(cw, cwT);

  rmsnorm_kernel<<<8192, 256, 0, stream>>>(x, gamma, nrm);

  // fused QKV: (8192x1024) @ (1024x3072) -> qkv (q,k) + Vt (V^T direct)
  gemm128_kernel<5><<<1536, 256, 0, stream>>>(nrm, 1024, wqkvT, nullptr, nullptr, qkv, nullptr, Vt, 3072, 1024, QSCALE, 64);

  attn_kernel<<<dim3(8, 128), 256, 0, stream>>>(qkv, Vt, mask, nrm);

  // out proj: ctx(nrm) @ wo -> ao
  gemm128_kernel<0><<<512, 256, 0, stream>>>(nrm, 1024, woT, nullptr, nullptr, ao, nullptr, nullptr, 1024, 1024, 1.0f, 64);

  // f = ao[:, :512] @ w1 + b1 ; sec = relu(ao[:, 512:] @ w2 + b2)
  gemm128_kernel<1><<<1024, 256, 0, stream>>>(ao,       1024, w1T, b1, nullptr, fbuf, nullptr, nullptr, 2048, 512, 1.0f, 64);
  gemm128_kernel<2><<<1024, 256, 0, stream>>>(ao + 512, 1024, w2T, b2, nullptr, sec,  nullptr, nullptr, 2048, 512, 1.0f, 64);

  convgate_kernel<<<8192, 256, 0, stream>>>(fbuf, cwT, cb, sec);

  // out = x + gated @ wp + bp
  gemm128_kernel<3><<<512, 256, 0, stream>>>(sec, 2048, wpT, bp, x, nullptr, out, nullptr, 1024, 2048, 1.0f, 64);
}

// Round 8
// 311.886 us; speedup vs baseline: 2.0754x; 1.0720x over previous
//
#include <hip/hip_runtime.h>

typedef unsigned short u16;
typedef __bf16 bf16x8 __attribute__((ext_vector_type(8)));
typedef short  s16x8  __attribute__((ext_vector_type(8)));
typedef float  f32x4  __attribute__((ext_vector_type(4)));

#define LDSPAD 72   // 64 + 8 bf16 pad (P^T tile)

// async global->LDS, 16B per lane, LDS dest = wave-uniform base + lane*16
#define GLOAD16(gp, lp) __builtin_amdgcn_global_load_lds( \
  (__attribute__((address_space(1))) unsigned int*)(unsigned long long)(const void*)(gp), \
  (__attribute__((address_space(3))) unsigned int*)(lp), 16, 0, 0)

static __device__ __forceinline__ u16 f2bf(float f){
  union { float f; unsigned int u; } v; v.f = f;
  unsigned int r = v.u + 0x7fffu + ((v.u >> 16) & 1u);
  return (u16)(r >> 16);
}
static __device__ __forceinline__ float bf2f(u16 u){
  union { unsigned int u; float f; } v; v.u = ((unsigned int)u) << 16; return v.f;
}
static __device__ __forceinline__ unsigned fbits(float f){
  union { float f; unsigned u; } v; v.f = f; return v.u;
}

// ---------------- weight transpose + fp32 -> bf16, 4 matrices via blockIdx.z ------------
__global__ __launch_bounds__(256) void wtrans4_kernel(
    const float* __restrict__ in0, const float* __restrict__ in1,
    const float* __restrict__ in2, const float* __restrict__ in3,
    u16* __restrict__ out0, u16* __restrict__ out1,
    u16* __restrict__ out2, u16* __restrict__ out3, int K, int N){
  __shared__ float tile[32][33];
  int z = blockIdx.z;
  const float* in = (z == 0) ? in0 : (z == 1) ? in1 : (z == 2) ? in2 : in3;
  u16* out = (z == 0) ? out0 : (z == 1) ? out1 : (z == 2) ? out2 : out3;
  int n0 = blockIdx.x * 32, k0 = blockIdx.y * 32;
  int tx = threadIdx.x, ty = threadIdx.y;     // block (32, 8)
  #pragma unroll
  for (int i = 0; i < 4; ++i)
    tile[ty + i*8][tx] = in[(size_t)(k0 + ty + i*8) * N + n0 + tx];
  __syncthreads();
  #pragma unroll
  for (int i = 0; i < 4; ++i)
    out[(size_t)(n0 + ty + i*8) * K + k0 + tx] = f2bf(tile[tx][ty + i*8]);
}

// ---------------- conv weight transpose: cw (2048,1,4) -> cwT (4,2048) ----------------
__global__ __launch_bounds__(256) void cwtrans_kernel(const float* __restrict__ cw,
                                                      float* __restrict__ cwT){
  int i = blockIdx.x * 256 + threadIdx.x;   // 8192
  int c = i >> 2, j = i & 3;
  cwT[j * 2048 + c] = cw[i];
}

// ---------------- RMSNorm: fp32 in -> bf16 out ----------------
__global__ __launch_bounds__(256) void rmsnorm_kernel(const float* __restrict__ x,
                                                      const float* __restrict__ gamma,
                                                      u16* __restrict__ out){
  int row = blockIdx.x;                        // 8192 rows, D=1024
  const float* xr = x + (size_t)row * 1024;
  int tid = threadIdx.x;
  float4 xv = *(const float4*)(xr + tid * 4);
  float ss = xv.x*xv.x + xv.y*xv.y + xv.z*xv.z + xv.w*xv.w;
  #pragma unroll
  for (int off = 1; off < 64; off <<= 1) ss += __shfl_xor(ss, off);
  __shared__ float wsum[4];
  if ((tid & 63) == 0) wsum[tid >> 6] = ss;
  __syncthreads();
  float tot = wsum[0] + wsum[1] + wsum[2] + wsum[3];
  float r = rsqrtf(tot * (1.0f/1024.0f) + 1e-6f);
  const float4 gv = *(const float4*)(gamma + tid * 4);
  u16* o = out + (size_t)row * 1024 + tid * 4;
  o[0] = f2bf(xv.x * r * gv.x);
  o[1] = f2bf(xv.y * r * gv.y);
  o[2] = f2bf(xv.z * r * gv.z);
  o[3] = f2bf(xv.w * r * gv.w);
}

// ---------------- 128x128 double-buffered bf16 GEMM: C = A(MxK) * Bt(NxK)^T --------
// Prefetch-before-compute, XOR-swizzled LDS (T2), linear dispatch.
// EPI: 0 ->bf16, 1 +bias->bf16, 2 +bias,relu->bf16, 3 +bias,+resid->fp32,
//      5 QKV fused: cols<1024 scaled ->outb, [1024,2048) ->outb,
//        n0>=2048 blocks -> vt[(col-2048)*8192 + row] via LDS transpose (coalesced)
template<int EPI>
__global__ __launch_bounds__(256) void gemm128_kernel(
    const u16* __restrict__ A, int lda,
    const u16* __restrict__ Bt,
    const float* __restrict__ bias,
    const float* __restrict__ resid,
    u16* __restrict__ outb, float* __restrict__ outf,
    u16* __restrict__ vt,
    int N, int K, float scale, int nm)
{
  __shared__ __align__(16) u16 As[2][128*64];
  __shared__ __align__(16) u16 Bs[2][128*64];
  int tid = threadIdx.x;
  int wid = tid >> 6, lane = tid & 63;
  int fr = lane & 15, fq = lane >> 4;
  int wr = wid >> 1, wc = wid & 1;
  int l = (int)blockIdx.x;               // linear, m-fastest (L3-friendly round-robin)
  int m0 = (l % nm) * 128, n0 = (l / nm) * 128;
  int srow = lane >> 3;            // dest row within 8-row group
  int csw  = (lane & 7) ^ srow;    // pre-swizzled source 16B-chunk (rule #21)
  int c7   = fr & 7;               // read-side row XOR
  f32x4 acc[4][4] = {};

  const u16* Abase = A  + (size_t)m0 * lda;
  const u16* Bbase = Bt + (size_t)n0 * K;

  auto STAGE = [&](int bsel, int kt){
    int k0 = kt << 6;
    #pragma unroll
    for (int i = 0; i < 4; ++i){
      int r = i*32 + wid*8;
      GLOAD16(Abase + (size_t)(r + srow) * lda + k0 + csw*8, &As[bsel][r*64]);
      GLOAD16(Bbase + (size_t)(r + srow) * K   + k0 + csw*8, &Bs[bsel][r*64]);
    }
  };

  int nt = K >> 6;
  STAGE(0, 0);
  __syncthreads();
  for (int kt = 0; kt < nt; ++kt){
    int cur = kt & 1;
    if (kt + 1 < nt) STAGE(cur ^ 1, kt + 1);   // prefetch overlaps with compute below
    #pragma unroll
    for (int ks = 0; ks < 2; ++ks){
      bf16x8 av[4], bv[4];
      #pragma unroll
      for (int mi = 0; mi < 4; ++mi)
        av[mi] = *(const bf16x8*)&As[cur][(wr*64 + mi*16 + fr)*64 + (((ks*4 + fq) ^ c7) * 8)];
      #pragma unroll
      for (int ni = 0; ni < 4; ++ni)
        bv[ni] = *(const bf16x8*)&Bs[cur][(wc*64 + ni*16 + fr)*64 + (((ks*4 + fq) ^ c7) * 8)];
      #pragma unroll
      for (int mi = 0; mi < 4; ++mi)
        #pragma unroll
        for (int ni = 0; ni < 4; ++ni)
          acc[mi][ni] = __builtin_amdgcn_mfma_f32_16x16x32_bf16(av[mi], bv[ni], acc[mi][ni], 0, 0, 0);
    }
    __syncthreads();   // drains prefetch; protects buf[cur] from next-iter overwrite
  }

  if (EPI == 5 && n0 >= 2048){
    // V^T epilogue: C-tile -> LDS transpose -> coalesced 16B writes into vt
    u16* Ct = &As[0][0];                 // 64 x 136 u16 view
    #pragma unroll
    for (int p = 0; p < 2; ++p){
      __syncthreads();
      if (wc == p){
        #pragma unroll
        for (int ni = 0; ni < 4; ++ni)
          #pragma unroll
          for (int mi = 0; mi < 4; ++mi){
            int cl = ni*16 + fr;
            int rl = wr*64 + mi*16 + fq*4;
            uint2 pk;
            pk.x = (unsigned)f2bf(acc[mi][ni][0]) | ((unsigned)f2bf(acc[mi][ni][1]) << 16);
            pk.y = (unsigned)f2bf(acc[mi][ni][2]) | ((unsigned)f2bf(acc[mi][ni][3]) << 16);
            *(uint2*)&Ct[cl*136 + rl] = pk;
          }
      }
      __syncthreads();
      #pragma unroll
      for (int ci = 0; ci < 4; ++ci){
        int qq = ci*256 + tid;           // 0..1023
        int c = qq >> 4, off = (qq & 15) * 8;
        uint4 v = *(const uint4*)&Ct[c*136 + off];
        *(uint4*)&vt[(size_t)(n0 - 2048 + p*64 + c) * 8192 + m0 + off] = v;
      }
    }
    return;
  }

  // D layout: row = fq*4 + j, col = fr
  #pragma unroll
  for (int ni = 0; ni < 4; ++ni){
    int col = n0 + wc*64 + ni*16 + fr;
    float bvv = (EPI >= 1 && EPI <= 3) ? bias[col] : 0.0f;
    float scl = (EPI == 5) ? ((col < 1024) ? scale : 1.0f) : scale;
    #pragma unroll
    for (int mi = 0; mi < 4; ++mi){
      #pragma unroll
      for (int j = 0; j < 4; ++j){
        int row = m0 + wr*64 + mi*16 + fq*4 + j;
        float vv = acc[mi][ni][j] * scl + bvv;
        if (EPI == 2) vv = fmaxf(vv, 0.0f);
        size_t idx = (size_t)row * N + col;
        if (EPI == 3) outf[idx] = vv + resid[idx];
        else          outb[idx] = f2bf(vv);
      }
    }
  }
}

// ---------------- fused flash attention (swapped-operand, reg-fragment, stage-overlap) ----
// qkv: (B*S, 3072) bf16, Q cols pre-scaled by 0.125*log2e. Vt: (1024, 8192) = V^T.
// ctx out: (B*S, 1024) bf16. 64 q-rows per block; XCD-chunked: all 16 q-blocks of one
// (b,h) land on the same XCD so its 256KB K/V stays L2-resident (16 groups = 4MB = L2).
__global__ __launch_bounds__(256) void attn_kernel(
    const u16* __restrict__ qkv, const u16* __restrict__ Vt,
    const int* __restrict__ mask, u16* __restrict__ ctx)
{
  __shared__ __align__(16) u16 Ks[64*64];
  __shared__ __align__(16) u16 Vs[64*64];
  __shared__ __align__(16) u16 Ps[64][LDSPAD];
  int tid = threadIdx.x;
  int wid = tid >> 6, lane = tid & 63;
  int fr = lane & 15, fq = lane >> 4;
  int i = (int)blockIdx.x;                       // 2048 blocks
  int wg = (i & 7) * 256 + (i >> 3);             // XCD-chunked bijection (T1)
  int bh = wg >> 4;
  int q0 = (wg & 15) * 64;
  int b = bh >> 4, h = bh & 15;

  const u16* qb  = qkv + (size_t)b * 1024 * 3072 + h * 64;          // + s*3072 + d
  const u16* kb  = qb + 1024;
  const u16* vtb = Vt + (size_t)(h * 64) * 8192 + b * 1024;         // + d*8192 + s

  int lrow = lane >> 3;                   // 0..7
  int cs   = (lane & 7) ^ lrow;           // pre-swizzled source 16B-chunk
  int wbase = wid * 16;
  int c7 = fr & 7;                        // read-side row XOR

  bf16x8 qf[2];
  {
    const u16* qp = qb + (size_t)(q0 + wid*16 + fr) * 3072 + fq * 8;
    qf[0] = *(const bf16x8*)(qp);
    qf[1] = *(const bf16x8*)(qp + 32);
  }
  f32x4 acc[4];
  #pragma unroll
  for (int k = 0; k < 4; ++k) acc[k] = (f32x4){0.f, 0.f, 0.f, 0.f};
  float mrun = -1e30f, lsum = 0.f;

  auto STAGE = [&](int t){
    int kv0 = t * 64;
    #pragma unroll
    for (int k = 0; k < 2; ++k){
      int r = wbase + k*8 + lrow;
      GLOAD16(kb  + (size_t)(kv0 + r) * 3072 + cs * 8, &Ks[(wbase + k*8) * 64]);
      GLOAD16(vtb + (size_t)r * 8192 + kv0 + cs * 8,   &Vs[(wbase + k*8) * 64]);
    }
  };

  STAGE(0);
  for (int t = 0; t < 16; ++t){
    int kv0 = t * 64;
    __syncthreads();                 // staged tile t visible
    // K,V fragments -> registers
    bf16x8 kf[2][4], vf[2][4];
    #pragma unroll
    for (int ks = 0; ks < 2; ++ks)
      #pragma unroll
      for (int nt = 0; nt < 4; ++nt){
        kf[ks][nt] = *(const bf16x8*)&Ks[(nt*16 + fr)*64 + (((ks*4 + fq) ^ c7) * 8)];
        vf[ks][nt] = *(const bf16x8*)&Vs[(nt*16 + fr)*64 + (((ks*4 + fq) ^ c7) * 8)];
      }
    // wave-uniform mask check for this KV tile (one dword per lane)
    int mv1 = mask[b * 1024 + kv0 + lane];
    __syncthreads();                 // all waves done reading LDS K/V
    if (t + 1 < 16) STAGE(t + 1);    // overwrite overlaps all compute below

    // QK^T (swapped): sc[nt][j] = S^T[k = nt*16+fq*4+j][q = wid*16+fr]
    f32x4 sc[4];
    #pragma unroll
    for (int nt = 0; nt < 4; ++nt) sc[nt] = (f32x4){0.f, 0.f, 0.f, 0.f};
    __builtin_amdgcn_s_setprio(1);
    #pragma unroll
    for (int ks = 0; ks < 2; ++ks)
      #pragma unroll
      for (int nt = 0; nt < 4; ++nt)
        sc[nt] = __builtin_amdgcn_mfma_f32_16x16x32_bf16(kf[ks][nt], qf[ks], sc[nt], 0, 0, 0);
    __builtin_amdgcn_s_setprio(0);

    if (!__all(mv1 != 0)){           // rare path: apply mask per score
      #pragma unroll
      for (int nt = 0; nt < 4; ++nt){
        int4 mv = *(const int4*)&mask[b * 1024 + kv0 + nt*16 + fq*4];
        int mvals[4] = {mv.x, mv.y, mv.z, mv.w};
        #pragma unroll
        for (int j = 0; j < 4; ++j)
          sc[nt][j] = mvals[j] ? sc[nt][j] : -1e9f;
      }
    }

    // in-lane softmax (log2 domain), tree max (max3-fusable)
    float m01 = fmaxf(fmaxf(sc[0][0], sc[0][1]), fmaxf(sc[0][2], sc[0][3]));
    float m11 = fmaxf(fmaxf(sc[1][0], sc[1][1]), fmaxf(sc[1][2], sc[1][3]));
    float m21 = fmaxf(fmaxf(sc[2][0], sc[2][1]), fmaxf(sc[2][2], sc[2][3]));
    float m31 = fmaxf(fmaxf(sc[3][0], sc[3][1]), fmaxf(sc[3][2], sc[3][3]));
    float pmax = fmaxf(fmaxf(m01, m11), fmaxf(m21, m31));
    pmax = fmaxf(pmax, __shfl_xor(pmax, 16));
    pmax = fmaxf(pmax, __shfl_xor(pmax, 32));
    if (!__all(pmax <= mrun + 8.0f)){            // defer-max (T13)
      float mnew = fmaxf(mrun, pmax);
      float corr = exp2f(mrun - mnew);
      #pragma unroll
      for (int nt = 0; nt < 4; ++nt)
        #pragma unroll
        for (int j = 0; j < 4; ++j)
          acc[nt][j] *= corr;
      lsum *= corr;
      mrun = mnew;
    }
    float p[4][4];
    float ls = 0.f;
    #pragma unroll
    for (int nt = 0; nt < 4; ++nt)
      #pragma unroll
      for (int j = 0; j < 4; ++j){
        float pv = exp2f(sc[nt][j] - mrun);
        p[nt][j] = pv;
        ls += pv;
      }
    lsum += ls;

    // P^T -> per-wave LDS rows (truncate-to-bf16 pairs via v_perm), same-wave ordering
    #pragma unroll
    for (int nt = 0; nt < 4; ++nt){
      unsigned d0 = __builtin_amdgcn_perm(fbits(p[nt][1]), fbits(p[nt][0]), 0x07060302u);
      unsigned d1 = __builtin_amdgcn_perm(fbits(p[nt][3]), fbits(p[nt][2]), 0x07060302u);
      *(unsigned*)&Ps[wid*16 + fr][nt*16 + fq*4]     = d0;
      *(unsigned*)&Ps[wid*16 + fr][nt*16 + fq*4 + 2] = d1;
    }

    // PV (swapped): acc[nt] += mfma(V^T frag (regs), P^T frag)
    __builtin_amdgcn_s_setprio(1);
    #pragma unroll
    for (int ks = 0; ks < 2; ++ks){
      bf16x8 pb = *(const bf16x8*)&Ps[wid*16 + fr][ks*32 + fq*8];
      #pragma unroll
      for (int nt = 0; nt < 4; ++nt)
        acc[nt] = __builtin_amdgcn_mfma_f32_16x16x32_bf16(vf[ks][nt], pb, acc[nt], 0, 0, 0);
    }
    __builtin_amdgcn_s_setprio(0);
  }

  lsum += __shfl_xor(lsum, 16);
  lsum += __shfl_xor(lsum, 32);
  float invl = 1.0f / lsum;

  // O^T write-back: d = nt*16+fq*4+j, q = wid*16+fr
  size_t rowbase = ((size_t)b * 1024 + q0 + wid*16 + fr) * 1024 + h * 64;
  #pragma unroll
  for (int nt = 0; nt < 4; ++nt){
    unsigned lo = (unsigned)f2bf(acc[nt][0] * invl) | ((unsigned)f2bf(acc[nt][1] * invl) << 16);
    unsigned hi = (unsigned)f2bf(acc[nt][2] * invl) | ((unsigned)f2bf(acc[nt][3] * invl) << 16);
    uint2 pk; pk.x = lo; pk.y = hi;
    *(uint2*)&ctx[rowbase + nt*16 + fq*4] = pk;
  }
}

// ---------------- depthwise dilated conv (K=4, dil=2, pad 3) + gate, in-place over sec ----------------
// cwT: (4, 2048) f32 transposed conv weights -> coalesced vector loads
__global__ __launch_bounds__(256) void convgate_kernel(
    const u16* __restrict__ f, const float* __restrict__ cwT,
    const float* __restrict__ cb, u16* __restrict__ sec_inout)
{
  size_t gid = (size_t)blockIdx.x * blockDim.x + threadIdx.x;  // 2M threads, 8 ch each
  int c0 = (int)(gid & 255) * 8;
  int t  = (int)((gid >> 8) & 1023);
  int b  = (int)(gid >> 18);
  const u16* fb = f + ((size_t)b * 1024) * 2048;

  // coalesced weight/bias loads (lane stride 32B)
  float4 w[4][2];
  #pragma unroll
  for (int j = 0; j < 4; ++j){
    w[j][0] = *(const float4*)&cwT[j*2048 + c0];
    w[j][1] = *(const float4*)&cwT[j*2048 + c0 + 4];
  }
  float4 cb0 = *(const float4*)&cb[c0];
  float4 cb1 = *(const float4*)&cb[c0 + 4];
  float acc[8] = {cb0.x, cb0.y, cb0.z, cb0.w, cb1.x, cb1.y, cb1.z, cb1.w};

  #pragma unroll
  for (int j = 0; j < 4; ++j){
    int tt = t - 3 + 2 * j;
    if (tt >= 0 && tt < 1024){     // block-uniform branch (t is block-uniform)
      s16x8 fv = *(const s16x8*)(fb + (size_t)tt * 2048 + c0);
      const float* wj = (const float*)&w[j][0];
      #pragma unroll
      for (int e = 0; e < 8; ++e) acc[e] += bf2f((u16)fv[e]) * wj[e];
    }
  }
  u16* sp = sec_inout + (((size_t)b * 1024 + t) * 2048 + c0);
  s16x8 sv = *(const s16x8*)sp;
  s16x8 ov;
  #pragma unroll
  for (int e = 0; e < 8; ++e) ov[e] = (short)f2bf(acc[e] * bf2f((u16)sv[e]));
  *(s16x8*)sp = ov;
}

// ---------------- host launch ----------------
extern "C" void kernel_launch(void* const* d_in, const int* in_sizes, int n_in,
                              void* d_out, int out_size, void* d_ws, size_t ws_size,
                              hipStream_t stream)
{
  const float* x     = (const float*)d_in[0];
  const int*   mask  = (const int*)  d_in[1];
  const float* gamma = (const float*)d_in[2];
  const float* wq    = (const float*)d_in[3];
  const float* wk    = (const float*)d_in[4];
  const float* wv    = (const float*)d_in[5];
  const float* wo    = (const float*)d_in[6];
  const float* w1    = (const float*)d_in[7];
  const float* b1    = (const float*)d_in[8];
  const float* cw    = (const float*)d_in[9];
  const float* cb    = (const float*)d_in[10];
  const float* w2    = (const float*)d_in[11];
  const float* b2    = (const float*)d_in[12];
  const float* wp    = (const float*)d_in[13];
  const float* bp    = (const float*)d_in[14];
  float* out = (float*)d_out;

  char* p = (char*)d_ws;
  auto alloc = [&](size_t bytes){ char* r = p; p += (bytes + 255) & ~(size_t)255; return r; };
  u16*   wqkvT = (u16*)alloc((size_t)3072*1024*2);  // wq^T | wk^T | wv^T contiguous
  u16*   woT   = (u16*)alloc((size_t)1024*1024*2);
  u16*   w1T   = (u16*)alloc((size_t)2048*512*2);
  u16*   w2T   = (u16*)alloc((size_t)2048*512*2);
  u16*   wpT   = (u16*)alloc((size_t)1024*2048*2);
  float* cwT   = (float*)alloc((size_t)4*2048*4);
  u16*   nrm   = (u16*)alloc((size_t)8192*1024*2);   // later: attn ctx
  u16*   qkv   = (u16*)alloc((size_t)8192*3072*2);   // later: [0:16MB] ao, [16:48MB] f
  u16*   sec   = (u16*)alloc((size_t)8192*2048*2);   // first 16MB doubles as Vt before w2 GEMM
  u16* Vt   = sec;
  u16* ao   = qkv;
  u16* fbuf = qkv + (size_t)8192*1024;
  (void)ws_size; (void)in_sizes; (void)n_in; (void)out_size;

  const float QSCALE = 0.125f * 1.44269504088896340736f;  // 1/sqrt(64) * log2(e)

  dim3 tb32(32, 8);
  wtrans4_kernel<<<dim3(32, 32, 4), tb32, 0, stream>>>(
      wq, wk, wv, wo,
      wqkvT, wqkvT + (size_t)1024*1024, wqkvT + (size_t)2048*1024, woT, 1024, 1024);
  wtrans4_kernel<<<dim3(64, 16, 2), tb32, 0, stream>>>(
      w1, w2, w1, w2, w1T, w2T, w1T, w2T, 512, 2048);
  wtrans4_kernel<<<dim3(32, 64, 1), tb32, 0, stream>>>(
      wp, wp, wp, wp, wpT, wpT, wpT, wpT, 2048, 1024);
  cwtrans_kernel<<<32, 256, 0, stream>>>(cw, cwT);

  rmsnorm_kernel<<<8192, 256, 0, stream>>>(x, gamma, nrm);

  // fused QKV: (8192x1024) @ (1024x3072) -> qkv (q,k) + Vt (V^T direct)
  gemm128_kernel<5><<<1536, 256, 0, stream>>>(nrm, 1024, wqkvT, nullptr, nullptr, qkv, nullptr, Vt, 3072, 1024, QSCALE, 64);

  attn_kernel<<<2048, 256, 0, stream>>>(qkv, Vt, mask, nrm);

  // out proj: ctx(nrm) @ wo -> ao
  gemm128_kernel<0><<<512, 256, 0, stream>>>(nrm, 1024, woT, nullptr, nullptr, ao, nullptr, nullptr, 1024, 1024, 1.0f, 64);

  // f = ao[:, :512] @ w1 + b1 ; sec = relu(ao[:, 512:] @ w2 + b2)
  gemm128_kernel<1><<<1024, 256, 0, stream>>>(ao,       1024, w1T, b1, nullptr, fbuf, nullptr, nullptr, 2048, 512, 1.0f, 64);
  gemm128_kernel<2><<<1024, 256, 0, stream>>>(ao + 512, 1024, w2T, b2, nullptr, sec,  nullptr, nullptr, 2048, 512, 1.0f, 64);

  convgate_kernel<<<8192, 256, 0, stream>>>(fbuf, cwT, cb, sec);

  // out = x + gated @ wp + bp
  gemm128_kernel<3><<<512, 256, 0, stream>>>(sec, 2048, wpT, bp, x, nullptr, out, nullptr, 1024, 2048, 1.0f, 64);
}